// Round 5
// baseline (303.778 us; speedup 1.0000x reference)
//
#include <hip/hip_runtime.h>
#include <cstddef>

constexpr int N_ = 65536;
constexpr int K_ = 16;
constexpr int E_ = N_ * K_;      // 1048576
constexpr int C_ = 64;
#define EPS_ 1e-5f
#define SW 68   // LDS row stride (words) for f32 y-tile
#define INV_N (1.f / 65536.f)
#define INV_E (1.f / 1048576.f)
#define NSLOT 64   // atomic-contention spread (R11 post-mortem: 4 lines -> 534us)

typedef unsigned int uint_t;
typedef float f32x4_t __attribute__((ext_vector_type(4)));
typedef short bf16x8_t __attribute__((ext_vector_type(8)));

// bf16 helpers (RNE pack, cheap unpack)
__device__ __forceinline__ uint_t bf16_rne(float f) {
    uint_t u = __float_as_uint(f);
    return (u + 0x7fffu + ((u >> 16) & 1u)) >> 16;
}
__device__ __forceinline__ float bf16_lo(uint_t p) { return __uint_as_float(p << 16); }
__device__ __forceinline__ float bf16_hi(uint_t p) { return __uint_as_float(p & 0xffff0000u); }
__device__ __forceinline__ uint_t pk2(float a, float b) {
    return bf16_rne(a) | (bf16_rne(b) << 16);
}
// HW packed RNE convert: dst = {bf16(hi)<<16 | bf16(lo)}
__device__ __forceinline__ uint_t cvtpk(float lo, float hi) {
    uint_t r;
    asm("v_cvt_pk_bf16_f32 %0, %1, %2" : "=v"(r) : "v"(lo), "v"(hi));
    return r;
}

// split f32x4 -> hi bf16x4 (packed uint2) + lo residual bf16x4 (packed uint2).
// x ~= hi + lo with |x - hi - lo| <~ 2^-18 |x|  -> split-bf16 GEMM == f32-level.
__device__ __forceinline__ void split4(float4 v, uint2& h, uint2& l) {
    h.x = cvtpk(v.x, v.y); h.y = cvtpk(v.z, v.w);
    float r0 = v.x - bf16_lo(h.x), r1 = v.y - bf16_hi(h.x);
    float r2 = v.z - bf16_lo(h.y), r3 = v.w - bf16_hi(h.y);
    l.x = cvtpk(r0, r1); l.y = cvtpk(r2, r3);
}

// scale/shift from raw summed {sum, sumsq}: s[c]=sum, s[nchp+c]=sumsq
__device__ __forceinline__ void bn_ss(const float* __restrict__ s, int nchp, int c,
                                      float invM, const float* __restrict__ g,
                                      const float* __restrict__ b,
                                      float& sc, float& sh)
{
    float mean = s[c] * invM;
    float var  = fmaxf(s[nchp + c] * invM - mean * mean, 0.f);
    sc = g[c] * rsqrtf(var + EPS_);
    sh = b[c] - mean * sc;
}

// ---------------------------------------------------------------------------
// R15 MFMA GEMM machinery. Tiles stored pre-split as bf16-hi / bf16-lo in
// uint[64][36] LDS. Fragment mapping = edge_t1-verified mfma_f32_16x16x32_bf16:
//   A-frag: lane L holds A[row=L&15][k=(L>>4)*8+j]
//   B-frag: lane L holds W[outcol=L&15][k=(L>>4)*8+j]
//   C     : row=(L>>4)*4+j, col=L&15
#define TS 36   // uint stride of split tiles

__device__ __forceinline__ void stage_x_split(const float* __restrict__ in,
                                              const float* __restrict__ ss,
                                              uint_t* __restrict__ Xh,
                                              uint_t* __restrict__ Xl,
                                              int row0, int t)
{
#pragma unroll
    for (int it = 0; it < 4; ++it) {
        int m = t + 256 * it;
        int r = m >> 4, j = m & 15;
        float4 v = ((const float4*)in)[(size_t)(row0 + r) * 16 + j];
        if (ss) {
            float4 sc = ((const float4*)ss)[j];
            float4 sh = ((const float4*)(ss + 64))[j];
            v.x = fmaxf(fmaf(v.x, sc.x, sh.x), 0.f);
            v.y = fmaxf(fmaf(v.y, sc.y, sh.y), 0.f);
            v.z = fmaxf(fmaf(v.z, sc.z, sh.z), 0.f);
            v.w = fmaxf(fmaf(v.w, sc.w, sh.w), 0.f);
        }
        uint2 h, l; split4(v, h, l);
        *(uint2*)&Xh[r * TS + 2 * j] = h;
        *(uint2*)&Xl[r * TS + 2 * j] = l;
    }
}

__device__ __forceinline__ void stage_w_split(const float* __restrict__ W,
                                              uint_t* __restrict__ Wh,
                                              uint_t* __restrict__ Wl, int t)
{
#pragma unroll
    for (int it = 0; it < 4; ++it) {
        int m = t + 256 * it;
        int r = m >> 4, j = m & 15;
        float4 v = ((const float4*)W)[m];
        uint2 h, l; split4(v, h, l);
        *(uint2*)&Wh[r * TS + 2 * j] = h;
        *(uint2*)&Wl[r * TS + 2 * j] = l;
    }
}

struct AFrag { uint4 h0, h1, l0, l1; };

__device__ __forceinline__ AFrag load_afrag(const uint_t* __restrict__ Xh,
                                            const uint_t* __restrict__ Xl,
                                            int L, int wv)
{
    int cl = L & 15, kb = L >> 4;
    int o = (16 * wv + cl) * TS + kb * 4;
    AFrag a;
    a.h0 = *(const uint4*)&Xh[o]; a.h1 = *(const uint4*)&Xh[o + 16];
    a.l0 = *(const uint4*)&Xl[o]; a.l1 = *(const uint4*)&Xl[o + 16];
    return a;
}

#define MF(A, B, C) __builtin_amdgcn_mfma_f32_16x16x32_bf16( \
        *(const bf16x8_t*)&(A), *(const bf16x8_t*)&(B), (C), 0, 0, 0)

// y = X @ W^T via split-bf16: Xh*Wh + Xl*Wh + Xh*Wl (lo*lo dropped).
__device__ __forceinline__ void mfma_tile(const AFrag& af,
                                          const uint_t* __restrict__ Wh,
                                          const uint_t* __restrict__ Wl,
                                          int L, f32x4_t acc[4])
{
    int cl = L & 15, kb = L >> 4;
#pragma unroll
    for (int ct = 0; ct < 4; ++ct) {
        int o = (ct * 16 + cl) * TS + kb * 4;
        uint4 Bh0 = *(const uint4*)&Wh[o], Bh1 = *(const uint4*)&Wh[o + 16];
        uint4 Bl0 = *(const uint4*)&Wl[o], Bl1 = *(const uint4*)&Wl[o + 16];
        f32x4_t a = {0.f, 0.f, 0.f, 0.f};
        a = MF(af.h0, Bh0, a); a = MF(af.l0, Bh0, a); a = MF(af.h0, Bl0, a);
        a = MF(af.h1, Bh1, a); a = MF(af.l1, Bh1, a); a = MF(af.h1, Bl1, a);
        acc[ct] = a;
    }
}

__device__ __forceinline__ void ytile_store(float* __restrict__ ybuf, int L, int wv,
                                            const f32x4_t acc[4])
{
    int cl = L & 15, kb = L >> 4;
#pragma unroll
    for (int ct = 0; ct < 4; ++ct)
#pragma unroll
        for (int j = 0; j < 4; ++j)
            ybuf[(16 * wv + kb * 4 + j) * SW + ct * 16 + cl] = acc[ct][j];
}

// y = (optional relu(bn_from_slots(in))) @ W^T, MFMA split-bf16.
// Output column stats -> slot-spread atomicAdd.
__global__ __launch_bounds__(256)
void k_gemm_tile(const float* __restrict__ in, const float* __restrict__ W,
                 const float* __restrict__ acc_in, const float* __restrict__ g_in,
                 const float* __restrict__ b_in, float invM_in,
                 float* __restrict__ out, float* __restrict__ acc_out)
{
    __shared__ __align__(16) uint_t shb[4 * 64 * TS];   // 36864 B
    __shared__ float ssm[128];
    __shared__ float raws[128];
    uint_t* Xh = shb;           uint_t* Xl = shb + 64 * TS;
    uint_t* Wh = shb + 2 * 64 * TS; uint_t* Wl = shb + 3 * 64 * TS;
    float* ybuf = (float*)shb;                        // [64][SW] f32, aliases Xh/Xl
    float4* scr = (float4*)((float*)shb + 4352);      // after ybuf; aliases Wh (reads done)
    int t = threadIdx.x, L = t & 63, wv = t >> 6;
    int row0 = blockIdx.x * 64;
    if (acc_in) {
        if (t < 128) {
            float s = 0.f;
            for (int sl = 0; sl < NSLOT; ++sl) s += acc_in[sl * 128 + t];
            raws[t] = s;
        }
        __syncthreads();
        if (t < 64) {
            float scv, shv;
            bn_ss(raws, 64, t, invM_in, g_in, b_in, scv, shv);
            ssm[t] = scv; ssm[64 + t] = shv;
        }
    }
    __syncthreads();
    stage_x_split(in, acc_in ? ssm : nullptr, Xh, Xl, row0, t);
    stage_w_split(W, Wh, Wl, t);
    __syncthreads();
    AFrag af = load_afrag(Xh, Xl, L, wv);
    f32x4_t acc[4];
    mfma_tile(af, Wh, Wl, L, acc);
    __syncthreads();            // all A/B tile reads done before ybuf overwrite
    ytile_store(ybuf, L, wv, acc);
    __syncthreads();
    float s0 = 0, s1 = 0, s2 = 0, s3 = 0, q0 = 0, q1 = 0, q2 = 0, q3 = 0;
#pragma unroll
    for (int it = 0; it < 4; ++it) {
        int m = t + 256 * it;
        int r = m >> 4, j = m & 15;
        float4 v = *(const float4*)&ybuf[r * SW + 4 * j];
        ((float4*)out)[(size_t)(row0 + r) * 16 + j] = v;
        s0 += v.x; q0 = fmaf(v.x, v.x, q0);
        s1 += v.y; q1 = fmaf(v.y, v.y, q1);
        s2 += v.z; q2 = fmaf(v.z, v.z, q2);
        s3 += v.w; q3 = fmaf(v.w, v.w, q3);
    }
    scr[t]       = make_float4(s0, s1, s2, s3);   // disjoint from ybuf reads
    scr[256 + t] = make_float4(q0, q1, q2, q3);
    __syncthreads();
    if (t < 16) {   // thread t handles channels 4t..4t+3
        float4 S = make_float4(0, 0, 0, 0), Q = make_float4(0, 0, 0, 0);
#pragma unroll
        for (int k = 0; k < 16; ++k) {
            float4 a = scr[k * 16 + t], b = scr[256 + k * 16 + t];
            S.x += a.x; S.y += a.y; S.z += a.z; S.w += a.w;
            Q.x += b.x; Q.y += b.y; Q.z += b.z; Q.w += b.w;
        }
        float* ao = acc_out + (blockIdx.x & (NSLOT - 1)) * 128;
        atomicAdd(&ao[4 * t + 0], S.x); atomicAdd(&ao[4 * t + 1], S.y);
        atomicAdd(&ao[4 * t + 2], S.z); atomicAdd(&ao[4 * t + 3], S.w);
        atomicAdd(&ao[64 + 4 * t + 0], Q.x); atomicAdd(&ao[64 + 4 * t + 1], Q.y);
        atomicAdd(&ao[64 + 4 * t + 2], Q.z); atomicAdd(&ao[64 + 4 * t + 3], Q.w);
    }
}

// h = relu(bn1(y)) [bn1 from slots]; asrc16 = bf16(h@Wa^T+ba);
// adst = h@Wb^T+bb (f32); hw16 = bf16(h@Wc^T+bc). All three GEMMs MFMA
// split-bf16; A-frags (h) loaded once into regs and reused.
__global__ __launch_bounds__(256)
void k_gemm3_tile(const float* __restrict__ y, const float* __restrict__ acc1,
                  const float* __restrict__ g1, const float* __restrict__ b1,
                  const float* __restrict__ Wa, const float* __restrict__ ba,
                  const float* __restrict__ Wb, const float* __restrict__ bb,
                  const float* __restrict__ Wc, const float* __restrict__ bc,
                  unsigned short* __restrict__ oa16, float* __restrict__ ob,
                  unsigned short* __restrict__ oc16)
{
    __shared__ __align__(16) uint_t shb[4 * 64 * TS];
    __shared__ float ssm[128];
    __shared__ float raws[128];
    uint_t* Xh = shb;           uint_t* Xl = shb + 64 * TS;
    uint_t* Wh = shb + 2 * 64 * TS; uint_t* Wl = shb + 3 * 64 * TS;
    float* ybuf = (float*)shb;
    int t = threadIdx.x, L = t & 63, wv = t >> 6;
    int row0 = blockIdx.x * 64;
    if (t < 128) {
        float s = 0.f;
        for (int sl = 0; sl < NSLOT; ++sl) s += acc1[sl * 128 + t];
        raws[t] = s;
    }
    __syncthreads();
    if (t < 64) {
        float scv, shv;
        bn_ss(raws, 64, t, INV_N, g1, b1, scv, shv);
        ssm[t] = scv; ssm[64 + t] = shv;
    }
    __syncthreads();
    stage_x_split(y, ssm, Xh, Xl, row0, t);
    stage_w_split(Wa, Wh, Wl, t);
    __syncthreads();
    AFrag af = load_afrag(Xh, Xl, L, wv);   // persists in regs across all 3 GEMMs
    f32x4_t acc[4];
    // ---- GEMM a -> bf16 out
    mfma_tile(af, Wh, Wl, L, acc);
    __syncthreads();
    ytile_store(ybuf, L, wv, acc);
    __syncthreads();
#pragma unroll
    for (int it = 0; it < 4; ++it) {
        int m = t + 256 * it;
        int r = m >> 4, j = m & 15;
        float4 v = *(const float4*)&ybuf[r * SW + 4 * j];
        float4 bv = ((const float4*)ba)[j];
        uint2 o;
        o.x = pk2(v.x + bv.x, v.y + bv.y);
        o.y = pk2(v.z + bv.z, v.w + bv.w);
        ((uint2*)oa16)[(size_t)(row0 + r) * 16 + j] = o;
    }
    __syncthreads();
    // ---- GEMM b -> f32 out
    stage_w_split(Wb, Wh, Wl, t);
    __syncthreads();
    mfma_tile(af, Wh, Wl, L, acc);
    __syncthreads();
    ytile_store(ybuf, L, wv, acc);
    __syncthreads();
#pragma unroll
    for (int it = 0; it < 4; ++it) {
        int m = t + 256 * it;
        int r = m >> 4, j = m & 15;
        float4 v = *(const float4*)&ybuf[r * SW + 4 * j];
        float4 bv = ((const float4*)bb)[j];
        v.x += bv.x; v.y += bv.y; v.z += bv.z; v.w += bv.w;
        ((float4*)ob)[(size_t)(row0 + r) * 16 + j] = v;
    }
    __syncthreads();
    // ---- GEMM c -> bf16 out
    stage_w_split(Wc, Wh, Wl, t);
    __syncthreads();
    mfma_tile(af, Wh, Wl, L, acc);
    __syncthreads();
    ytile_store(ybuf, L, wv, acc);
    __syncthreads();
#pragma unroll
    for (int it = 0; it < 4; ++it) {
        int m = t + 256 * it;
        int r = m >> 4, j = m & 15;
        float4 v = *(const float4*)&ybuf[r * SW + 4 * j];
        float4 bv = ((const float4*)bc)[j];
        uint2 o;
        o.x = pk2(v.x + bv.x, v.y + bv.y);
        o.y = pk2(v.z + bv.z, v.w + bv.w);
        ((uint2*)oc16)[(size_t)(row0 + r) * 16 + j] = o;
    }
}

// ---------------------------------------------------------------------------
// Stats of u = rel @ pos_w1^T + pos_b1 over E edges -> slot atomics (8/slot32).
__global__ __launch_bounds__(256)
void k_pos_stats(const float* __restrict__ pos, const int* __restrict__ src,
                 const float* __restrict__ pw1, const float* __restrict__ pb1,
                 float* __restrict__ acc)
{
    float s0 = 0, s1 = 0, s2 = 0, q0 = 0, q1 = 0, q2 = 0;
    int tid = blockIdx.x * 256 + threadIdx.x;
    for (int e = tid; e < E_; e += 1024 * 256) {
        int si = src[e], di = e >> 4;
        float rx = pos[3 * si + 0] - pos[3 * di + 0];
        float ry = pos[3 * si + 1] - pos[3 * di + 1];
        float rz = pos[3 * si + 2] - pos[3 * di + 2];
        float u0 = fmaf(rx, pw1[0], fmaf(ry, pw1[1], fmaf(rz, pw1[2], pb1[0])));
        float u1 = fmaf(rx, pw1[3], fmaf(ry, pw1[4], fmaf(rz, pw1[5], pb1[1])));
        float u2 = fmaf(rx, pw1[6], fmaf(ry, pw1[7], fmaf(rz, pw1[8], pb1[2])));
        s0 += u0; q0 = fmaf(u0, u0, q0);
        s1 += u1; q1 = fmaf(u1, u1, q1);
        s2 += u2; q2 = fmaf(u2, u2, q2);
    }
#pragma unroll
    for (int m = 1; m < 64; m <<= 1) {
        s0 += __shfl_xor(s0, m, 64); s1 += __shfl_xor(s1, m, 64); s2 += __shfl_xor(s2, m, 64);
        q0 += __shfl_xor(q0, m, 64); q1 += __shfl_xor(q1, m, 64); q2 += __shfl_xor(q2, m, 64);
    }
    __shared__ float red[4][8];
    int wv = threadIdx.x >> 6, ln = threadIdx.x & 63;
    if (ln == 0) {
        red[wv][0] = s0; red[wv][1] = s1; red[wv][2] = s2; red[wv][3] = 0.f;
        red[wv][4] = q0; red[wv][5] = q1; red[wv][6] = q2; red[wv][7] = 0.f;
    }
    __syncthreads();
    if (threadIdx.x < 8)
        atomicAdd(&acc[(blockIdx.x & (NSLOT - 1)) * 32 + threadIdx.x],
                  red[0][threadIdx.x] + red[1][threadIdx.x] + red[2][threadIdx.x] + red[3][threadIdx.x]);
}

// ---------------------------------------------------------------------------
// Stats of a = bf16(a_src)[src]-a_dst[dst]+delta. Grid 2048 x 256.
// R16: all 16 gathers hoisted ahead of the compute loop (16 outstanding VMEM
// ops/wave vs ~1-2 interleaved) — latency-regime fix; pb folded into dv/node.
__global__ __launch_bounds__(256)
void k_abn1_stats(const float* __restrict__ pos, const int* __restrict__ src,
                  const unsigned short* __restrict__ asrc16,
                  const float* __restrict__ adst,
                  const float* __restrict__ pw1, const float* __restrict__ pb1,
                  const float* __restrict__ accpos, const float* __restrict__ pbg,
                  const float* __restrict__ pbb, const float* __restrict__ pw2,
                  const float* __restrict__ pb2, float* __restrict__ acc_a1)
{
    __shared__ float rawP[8];
    int t = threadIdx.x;
    int l = t & 15, g = t >> 4, wv = t >> 6;
    int c0 = 4 * l;
    if (t < 8) {
        float s = 0.f;
        for (int sl = 0; sl < NSLOT; ++sl) s += accpos[sl * 32 + t];
        rawP[t] = s;
    }
    __syncthreads();
    float ps0, ph0, ps1, ph1, ps2, ph2;
    bn_ss(rawP, 4, 0, INV_E, pbg, pbb, ps0, ph0);
    bn_ss(rawP, 4, 1, INV_E, pbg, pbb, ps1, ph1);
    bn_ss(rawP, 4, 2, INV_E, pbg, pbb, ps2, ph2);
    float4 p0 = *(const float4*)(pw2 + 12 * l);
    float4 p1 = *(const float4*)(pw2 + 12 * l + 4);
    float4 p2 = *(const float4*)(pw2 + 12 * l + 8);
    float4 pb = *(const float4*)(pb2 + c0);
    float sa0 = 0, sa1 = 0, sa2 = 0, sa3 = 0;
    float qa0 = 0, qa1 = 0, qa2 = 0, qa3 = 0;
#pragma unroll
    for (int nn = 0; nn < 2; ++nn) {
        int n = blockIdx.x * 32 + nn * 16 + g;
        float4 dv = *(const float4*)(adst + (size_t)n * 64 + c0);
        float q0n = pb.x - dv.x, q1n = pb.y - dv.y;
        float q2n = pb.z - dv.z, q3n = pb.w - dv.w;
        float pnx = pos[3 * n + 0], pny = pos[3 * n + 1], pnz = pos[3 * n + 2];
        int si_l = src[n * 16 + l];
        float rx = pos[3 * si_l + 0] - pnx;
        float ry = pos[3 * si_l + 1] - pny;
        float rz = pos[3 * si_l + 2] - pnz;
        float u0 = fmaf(rx, pw1[0], fmaf(ry, pw1[1], fmaf(rz, pw1[2], pb1[0])));
        float u1 = fmaf(rx, pw1[3], fmaf(ry, pw1[4], fmaf(rz, pw1[5], pb1[1])));
        float u2 = fmaf(rx, pw1[6], fmaf(ry, pw1[7], fmaf(rz, pw1[8], pb1[2])));
        float dl0 = fmaxf(fmaf(u0, ps0, ph0), 0.f);
        float dl1 = fmaxf(fmaf(u1, ps1, ph1), 0.f);
        float dl2 = fmaxf(fmaf(u2, ps2, ph2), 0.f);
        uint2 raws16[16];
#pragma unroll
        for (int k = 0; k < 16; ++k) {
            int si = __shfl(si_l, k, 16);
            raws16[k] = ((const uint2*)asrc16)[(size_t)si * 16 + l];
        }
#pragma unroll
        for (int k = 0; k < 16; ++k) {
            float d0 = __shfl(dl0, k, 16);
            float d1 = __shfl(dl1, k, 16);
            float d2 = __shfl(dl2, k, 16);
            uint2 raw = raws16[k];
            float avx = bf16_lo(raw.x), avy = bf16_hi(raw.x);
            float avz = bf16_lo(raw.y), avw = bf16_hi(raw.y);
            float a0 = avx + fmaf(d0, p0.x, fmaf(d1, p0.y, fmaf(d2, p0.z, q0n)));
            float a1 = avy + fmaf(d0, p0.w, fmaf(d1, p1.x, fmaf(d2, p1.y, q1n)));
            float a2 = avz + fmaf(d0, p1.z, fmaf(d1, p1.w, fmaf(d2, p2.x, q2n)));
            float a3 = avw + fmaf(d0, p2.y, fmaf(d1, p2.z, fmaf(d2, p2.w, q3n)));
            sa0 += a0; qa0 = fmaf(a0, a0, qa0);
            sa1 += a1; qa1 = fmaf(a1, a1, qa1);
            sa2 += a2; qa2 = fmaf(a2, a2, qa2);
            sa3 += a3; qa3 = fmaf(a3, a3, qa3);
        }
    }
#pragma unroll
    for (int m = 16; m <= 32; m <<= 1) {
        sa0 += __shfl_xor(sa0, m, 64); sa1 += __shfl_xor(sa1, m, 64);
        sa2 += __shfl_xor(sa2, m, 64); sa3 += __shfl_xor(sa3, m, 64);
        qa0 += __shfl_xor(qa0, m, 64); qa1 += __shfl_xor(qa1, m, 64);
        qa2 += __shfl_xor(qa2, m, 64); qa3 += __shfl_xor(qa3, m, 64);
    }
    __shared__ float red[4][128];
    if ((t & 63) < 16) {
        red[wv][c0 + 0] = sa0; red[wv][c0 + 1] = sa1;
        red[wv][c0 + 2] = sa2; red[wv][c0 + 3] = sa3;
        red[wv][64 + c0 + 0] = qa0; red[wv][64 + c0 + 1] = qa1;
        red[wv][64 + c0 + 2] = qa2; red[wv][64 + c0 + 3] = qa3;
    }
    __syncthreads();
    if (t < 128)
        atomicAdd(&acc_a1[(blockIdx.x & (NSLOT - 1)) * 128 + t],
                  red[0][t] + red[1][t] + red[2][t] + red[3][t]);
}

// ---------------------------------------------------------------------------
// t1 = relu(abn1(a)) @ attn_w1^T + attn_b1; abn2 stats -> slot atomics.
// R14 structure + R16 gather-hoist; t1 stored bf16 (stats on pre-round f32).
__global__ __launch_bounds__(256)
void k_edge_t1(const float* __restrict__ pos, const int* __restrict__ src,
               const unsigned short* __restrict__ asrc16,
               const float* __restrict__ adst,
               const float* __restrict__ pw1, const float* __restrict__ pb1,
               const float* __restrict__ accpos, const float* __restrict__ pbg,
               const float* __restrict__ pbb, const float* __restrict__ pw2,
               const float* __restrict__ pb2, const float* __restrict__ acc_a1,
               const float* __restrict__ a1g, const float* __restrict__ a1b,
               const float* __restrict__ aw1, const float* __restrict__ ab1,
               unsigned short* __restrict__ t1, float* __restrict__ acc_a2)
{
    __shared__ uint2 an_lds[4096];   // 32KB: 16 tiles; head aliases rawA1/rawP, later red
    float* shf = (float*)an_lds;
    char*  anb = (char*)an_lds;
    int t = threadIdx.x;
    int l = t & 15, g = t >> 4, wv = t >> 6;
    int L = t & 63;
    int c0 = 4 * l;
    if (t < 128) {
        float s = 0.f;
        for (int sl = 0; sl < NSLOT; ++sl) s += acc_a1[sl * 128 + t];
        shf[t] = s;          // rawA1[0..127]
    } else if (t < 136) {
        int i = t - 128;
        float s = 0.f;
        for (int sl = 0; sl < NSLOT; ++sl) s += accpos[sl * 32 + i];
        shf[128 + i] = s;    // rawP[0..7]
    }
    __syncthreads();
    float ps0, ph0, ps1, ph1, ps2, ph2;
    bn_ss(shf + 128, 4, 0, INV_E, pbg, pbb, ps0, ph0);
    bn_ss(shf + 128, 4, 1, INV_E, pbg, pbb, ps1, ph1);
    bn_ss(shf + 128, 4, 2, INV_E, pbg, pbb, ps2, ph2);
    float scx, shx, scy, shy, scz, shz, scw, shw;
    bn_ss(shf, 64, c0 + 0, INV_E, a1g, a1b, scx, shx);
    bn_ss(shf, 64, c0 + 1, INV_E, a1g, a1b, scy, shy);
    bn_ss(shf, 64, c0 + 2, INV_E, a1g, a1b, scz, shz);
    bn_ss(shf, 64, c0 + 3, INV_E, a1g, a1b, scw, shw);
    // fold BN scale into pw2 rows + pb2:
    // an_c = max(av_c*sc_c + d.(pw2_c*sc_c) + (pb2_c*sc_c + sh_c - dv_c*sc_c), 0)
    float4 p0 = *(const float4*)(pw2 + 12 * l);
    float4 p1 = *(const float4*)(pw2 + 12 * l + 4);
    float4 p2 = *(const float4*)(pw2 + 12 * l + 8);
    float4 pb = *(const float4*)(pb2 + c0);
    float Pa0 = p0.x * scx, Pa1 = p0.y * scx, Pa2 = p0.z * scx;
    float Pb0 = p0.w * scy, Pb1 = p1.x * scy, Pb2 = p1.y * scy;
    float Pc0 = p1.z * scz, Pc1 = p1.w * scz, Pc2 = p2.x * scz;
    float Pd0 = p2.y * scw, Pd1 = p2.z * scw, Pd2 = p2.w * scw;
    float qb0 = fmaf(pb.x, scx, shx);
    float qb1 = fmaf(pb.y, scy, shy);
    float qb2 = fmaf(pb.z, scz, shz);
    float qb3 = fmaf(pb.w, scw, shw);
    // B fragment: lane holds w1[col = L&15][k = (L>>4)*8 + j], 2 K-halves, cols 8..15 zero.
    int col = L & 15, kb = L >> 4;
    uint4 bf0 = make_uint4(0u, 0u, 0u, 0u);
    uint4 bf1 = make_uint4(0u, 0u, 0u, 0u);
    float biasc = 0.f;
    if (col < 8) {
        const float* wr = aw1 + col * 64 + kb * 8;
        bf0 = make_uint4(pk2(wr[0], wr[1]), pk2(wr[2], wr[3]),
                         pk2(wr[4], wr[5]), pk2(wr[6], wr[7]));
        const float* wr2 = wr + 32;
        bf1 = make_uint4(pk2(wr2[0], wr2[1]), pk2(wr2[2], wr2[3]),
                         pk2(wr2[4], wr2[5]), pk2(wr2[6], wr2[7]));
        biasc = ab1[col];
    }
    // A-frag read offsets (bytes within a 2KB tile), XOR-swizzled by row&7.
    int ar = col;
    int aoff0 = ar * 128 + ((kb * 16) ^ ((ar & 7) << 4));
    int aoff1 = ar * 128 + ((64 + kb * 16) ^ ((ar & 7) << 4));
    __syncthreads();   // rawA1/rawP consumed into registers; tiles may overwrite
    float se = 0.f, sq = 0.f;
#pragma unroll
    for (int nn = 0; nn < 2; ++nn) {
        int n = blockIdx.x * 32 + nn * 16 + g;
        float4 dv = *(const float4*)(adst + (size_t)n * 64 + c0);
        float q0n = fmaf(-dv.x, scx, qb0);
        float q1n = fmaf(-dv.y, scy, qb1);
        float q2n = fmaf(-dv.z, scz, qb2);
        float q3n = fmaf(-dv.w, scw, qb3);
        float pnx = pos[3 * n + 0], pny = pos[3 * n + 1], pnz = pos[3 * n + 2];
        int si_l = src[n * 16 + l];
        float rx = pos[3 * si_l + 0] - pnx;
        float ry = pos[3 * si_l + 1] - pny;
        float rz = pos[3 * si_l + 2] - pnz;
        float u0 = fmaf(rx, pw1[0], fmaf(ry, pw1[1], fmaf(rz, pw1[2], pb1[0])));
        float u1 = fmaf(rx, pw1[3], fmaf(ry, pw1[4], fmaf(rz, pw1[5], pb1[1])));
        float u2 = fmaf(rx, pw1[6], fmaf(ry, pw1[7], fmaf(rz, pw1[8], pb1[2])));
        float dl0 = fmaxf(fmaf(u0, ps0, ph0), 0.f);
        float dl1 = fmaxf(fmaf(u1, ps1, ph1), 0.f);
        float dl2 = fmaxf(fmaf(u2, ps2, ph2), 0.f);
        uint2 raws16[16];
#pragma unroll
        for (int k = 0; k < 16; ++k) {
            int si = __shfl(si_l, k, 16);
            raws16[k] = ((const uint2*)asrc16)[(size_t)si * 16 + l];
        }
#pragma unroll
        for (int k = 0; k < 16; ++k) {
            float d0 = __shfl(dl0, k, 16);
            float d1 = __shfl(dl1, k, 16);
            float d2 = __shfl(dl2, k, 16);
            uint2 raw = raws16[k];
            float avx = bf16_lo(raw.x), avy = bf16_hi(raw.x);
            float avz = bf16_lo(raw.y), avw = bf16_hi(raw.y);
            float de0 = fmaf(d0, Pa0, fmaf(d1, Pa1, fmaf(d2, Pa2, q0n)));
            float de1 = fmaf(d0, Pb0, fmaf(d1, Pb1, fmaf(d2, Pb2, q1n)));
            float de2 = fmaf(d0, Pc0, fmaf(d1, Pc1, fmaf(d2, Pc2, q2n)));
            float de3 = fmaf(d0, Pd0, fmaf(d1, Pd1, fmaf(d2, Pd2, q3n)));
            float an0 = fmaxf(fmaf(avx, scx, de0), 0.f);
            float an1 = fmaxf(fmaf(avy, scy, de1), 0.f);
            float an2 = fmaxf(fmaf(avz, scz, de2), 0.f);
            float an3 = fmaxf(fmaf(avw, scw, de3), 0.f);
            // pack 4 ch -> bf16 and store to swizzled A tile (wave-local dep)
            int woff = g * 2048 + k * 128 + ((8 * l) ^ ((k & 7) << 4));
            *(uint2*)(anb + woff) = make_uint2(cvtpk(an0, an1), cvtpk(an2, an3));
        }
        // --- MFMA phase: this wave's 4 node-tiles (no cross-wave LDS deps)
#pragma unroll
        for (int tt = 0; tt < 4; ++tt) {
            int g2 = (wv << 2) + tt;
            int tb = g2 * 2048;
            uint4 a0 = *(const uint4*)(anb + tb + aoff0);
            uint4 a1v = *(const uint4*)(anb + tb + aoff1);
            f32x4_t acc = {0.f, 0.f, 0.f, 0.f};
            acc = __builtin_amdgcn_mfma_f32_16x16x32_bf16(
                      *(const bf16x8_t*)&a0, *(const bf16x8_t*)&bf0, acc, 0, 0, 0);
            acc = __builtin_amdgcn_mfma_f32_16x16x32_bf16(
                      *(const bf16x8_t*)&a1v, *(const bf16x8_t*)&bf1, acc, 0, 0, 0);
            if (col < 8) {
                int n2 = blockIdx.x * 32 + nn * 16 + g2;
                unsigned short* op = t1 + (size_t)(n2 * 16 + kb * 4) * 8 + col;
#pragma unroll
                for (int j = 0; j < 4; ++j) {
                    float v = acc[j] + biasc;
                    op[j * 8] = (unsigned short)bf16_rne(v);
                    se += v; sq = fmaf(v, v, sq);
                }
            }
        }
    }
    se += __shfl_xor(se, 16, 64); sq += __shfl_xor(sq, 16, 64);
    se += __shfl_xor(se, 32, 64); sq += __shfl_xor(sq, 32, 64);
    __syncthreads();   // all MFMA tile reads done; reuse LDS head as red[4][16]
    if (L < 8) { shf[wv * 16 + col] = se; shf[wv * 16 + 8 + col] = sq; }
    __syncthreads();
    if (t < 16)
        atomicAdd(&acc_a2[(blockIdx.x & (NSLOT - 1)) * 32 + t],
                  shf[t] + shf[16 + t] + shf[32 + t] + shf[48 + t]);
}

// ---------------------------------------------------------------------------
// Softmax + weighted aggregate, group-per-node; bn2 stats -> slot atomics.
// Grid 4096 x 256 (16 nodes/blk). R16: hw16 gathers hoisted; t1 read as bf16.
__global__ __launch_bounds__(256)
void k_node_aggr(const float* __restrict__ pos, const int* __restrict__ src,
                 const unsigned short* __restrict__ t1, const float* __restrict__ acc_a2,
                 const float* __restrict__ a2g, const float* __restrict__ a2b,
                 const float* __restrict__ aw2, const float* __restrict__ ab2,
                 const unsigned short* __restrict__ hw16,
                 const float* __restrict__ accpos, const float* __restrict__ pbg,
                 const float* __restrict__ pbb,
                 const float* __restrict__ pw1, const float* __restrict__ pb1,
                 const float* __restrict__ pw2, const float* __restrict__ pb2,
                 float* __restrict__ out, float* __restrict__ acc_bn2)
{
    __shared__ float alds[16][196];   // [group][k*12 + ch8]; later stats scratch
    __shared__ float ssm2[16];
    __shared__ float rawA2[16];
    __shared__ float rawP[8];
    int t = threadIdx.x, l = t & 15, g = t >> 4;
    int c0 = 4 * l;
    if (t < 16) {
        float s = 0.f;
        for (int sl = 0; sl < NSLOT; ++sl) s += acc_a2[sl * 32 + t];
        rawA2[t] = s;
    } else if (t < 24) {
        int i = t - 16;
        float s = 0.f;
        for (int sl = 0; sl < NSLOT; ++sl) s += accpos[sl * 32 + i];
        rawP[i] = s;
    }
    __syncthreads();
    if (t < 8) {
        float scv, shv;
        bn_ss(rawA2, 8, t, INV_E, a2g, a2b, scv, shv);
        ssm2[t] = scv; ssm2[8 + t] = shv;
    }
    __syncthreads();
    float ps0, ph0, ps1, ph1, ps2, ph2;
    bn_ss(rawP, 4, 0, INV_E, pbg, pbb, ps0, ph0);
    bn_ss(rawP, 4, 1, INV_E, pbg, pbb, ps1, ph1);
    bn_ss(rawP, 4, 2, INV_E, pbg, pbb, ps2, ph2);
    float4 p0 = *(const float4*)(pw2 + 12 * l);
    float4 p1 = *(const float4*)(pw2 + 12 * l + 4);
    float4 p2 = *(const float4*)(pw2 + 12 * l + 8);
    float4 pb = *(const float4*)(pb2 + c0);
    int alof = (l & 1) * 4;
    int n = blockIdx.x * 16 + g;
    int e = n * 16 + l;
    // ---- phase A: per-edge attention logits + softmax over the group
    uint4 t4 = ((const uint4*)t1)[e];
    float tv[8] = {bf16_lo(t4.x), bf16_hi(t4.x), bf16_lo(t4.y), bf16_hi(t4.y),
                   bf16_lo(t4.z), bf16_hi(t4.z), bf16_lo(t4.w), bf16_hi(t4.w)};
    float tn[8];
#pragma unroll
    for (int j = 0; j < 8; ++j)
        tn[j] = fmaxf(fmaf(tv[j], ssm2[j], ssm2[8 + j]), 0.f);
    float al[8];
#pragma unroll
    for (int j = 0; j < 8; ++j) {
        float acc = ab2[j];
#pragma unroll
        for (int i = 0; i < 8; ++i) acc = fmaf(tn[i], aw2[j * 8 + i], acc);
        float m = acc;
#pragma unroll
        for (int msk = 1; msk < 16; msk <<= 1) m = fmaxf(m, __shfl_xor(m, msk, 64));
        float ex = __expf(acc - m);
        float sm = ex;
#pragma unroll
        for (int msk = 1; msk < 16; msk <<= 1) sm += __shfl_xor(sm, msk, 64);
        al[j] = ex / sm;
    }
    *(float4*)&alds[g][l * 12]     = make_float4(al[0], al[1], al[2], al[3]);
    *(float4*)&alds[g][l * 12 + 4] = make_float4(al[4], al[5], al[6], al[7]);
    int silane = src[e];
    float pnx = pos[3 * n + 0], pny = pos[3 * n + 1], pnz = pos[3 * n + 2];
    // own-edge d
    float rx = pos[3 * silane + 0] - pnx;
    float ry = pos[3 * silane + 1] - pny;
    float rz = pos[3 * silane + 2] - pnz;
    float u0 = fmaf(rx, pw1[0], fmaf(ry, pw1[1], fmaf(rz, pw1[2], pb1[0])));
    float u1 = fmaf(rx, pw1[3], fmaf(ry, pw1[4], fmaf(rz, pw1[5], pb1[1])));
    float u2 = fmaf(rx, pw1[6], fmaf(ry, pw1[7], fmaf(rz, pw1[8], pb1[2])));
    float dl0 = fmaxf(fmaf(u0, ps0, ph0), 0.f);
    float dl1 = fmaxf(fmaf(u1, ps1, ph1), 0.f);
    float dl2 = fmaxf(fmaf(u2, ps2, ph2), 0.f);
    // hoist the 16 hw16 gathers (addresses known from shfl of silane)
    uint2 hraw[16];
#pragma unroll
    for (int k = 0; k < 16; ++k) {
        int sk = __shfl(silane, k, 16);
        hraw[k] = ((const uint2*)hw16)[(size_t)sk * 16 + l];
    }
    // ---- phase B: accumulate own 4 channels over the node's 16 edges
    float a0 = 0.f, a1 = 0.f, a2 = 0.f, a3 = 0.f;
#pragma unroll
    for (int k = 0; k < 16; ++k) {
        float d0 = __shfl(dl0, k, 16);
        float d1 = __shfl(dl1, k, 16);
        float d2 = __shfl(dl2, k, 16);
        uint2 raw = hraw[k];
        float hvx = bf16_lo(raw.x), hvy = bf16_hi(raw.x);
        float hvz = bf16_lo(raw.y), hvw = bf16_hi(raw.y);
        float4 alv = *(const float4*)&alds[g][k * 12 + alof];
        float del0 = fmaf(d0, p0.x, fmaf(d1, p0.y, fmaf(d2, p0.z, pb.x)));
        float del1 = fmaf(d0, p0.w, fmaf(d1, p1.x, fmaf(d2, p1.y, pb.y)));
        float del2 = fmaf(d0, p1.z, fmaf(d1, p1.w, fmaf(d2, p2.x, pb.z)));
        float del3 = fmaf(d0, p2.y, fmaf(d1, p2.z, fmaf(d2, p2.w, pb.w)));
        a0 = fmaf(alv.x, hvx + del0, a0);
        a1 = fmaf(alv.y, hvy + del1, a1);
        a2 = fmaf(alv.z, hvz + del2, a2);
        a3 = fmaf(alv.w, hvw + del3, a3);
    }
    *(float4*)(out + (size_t)n * 64 + c0) = make_float4(a0, a1, a2, a3);
    // ---- bn2 stats: reduce over the block's 16 nodes per channel
    __syncthreads();   // all alds reads done
    float4* scr = (float4*)&alds[0][0];   // 512 float4 <= 3136 floats OK
    scr[g * 16 + l]       = make_float4(a0, a1, a2, a3);
    scr[256 + g * 16 + l] = make_float4(a0 * a0, a1 * a1, a2 * a2, a3 * a3);
    __syncthreads();
    if (t < 16) {   // thread t handles channels 4t..4t+3
        float4 S = make_float4(0, 0, 0, 0), Q = make_float4(0, 0, 0, 0);
#pragma unroll
        for (int k = 0; k < 16; ++k) {
            float4 a = scr[k * 16 + t], b = scr[256 + k * 16 + t];
            S.x += a.x; S.y += a.y; S.z += a.z; S.w += a.w;
            Q.x += b.x; Q.y += b.y; Q.z += b.z; Q.w += b.w;
        }
        float* ao = acc_bn2 + (blockIdx.x & (NSLOT - 1)) * 128;
        atomicAdd(&ao[4 * t + 0], S.x); atomicAdd(&ao[4 * t + 1], S.y);
        atomicAdd(&ao[4 * t + 2], S.z); atomicAdd(&ao[4 * t + 3], S.w);
        atomicAdd(&ao[64 + 4 * t + 0], Q.x); atomicAdd(&ao[64 + 4 * t + 1], Q.y);
        atomicAdd(&ao[64 + 4 * t + 2], Q.z); atomicAdd(&ao[64 + 4 * t + 3], Q.w);
    }
}

// ---------------------------------------------------------------------------
// out = relu(bn3(y3) + x_skip); bn3 from slots.
__global__ __launch_bounds__(256)
void k_final(const float* __restrict__ y3, const float* __restrict__ acc3,
             const float* __restrict__ g3, const float* __restrict__ b3,
             const float* __restrict__ x, float* __restrict__ out)
{
    __shared__ float raws[128];
    __shared__ float ssl[128];
    int t = threadIdx.x;
    if (t < 128) {
        float s = 0.f;
        for (int sl = 0; sl < NSLOT; ++sl) s += acc3[sl * 128 + t];
        raws[t] = s;
    }
    __syncthreads();
    if (t < 64) {
        float scv, shv;
        bn_ss(raws, 64, t, INV_N, g3, b3, scv, shv);
        ssl[t] = scv; ssl[64 + t] = shv;
    }
    __syncthreads();
    int i = blockIdx.x * 256 + t;   // float4 index
    int c4 = i & 15;
    float4 sc = *(const float4*)&ssl[4 * c4];
    float4 sh = *(const float4*)&ssl[64 + 4 * c4];
    float4 v  = ((const float4*)y3)[i];
    float4 xs = ((const float4*)x)[i];
    float4 o;
    o.x = fmaxf(fmaf(v.x, sc.x, sh.x) + xs.x, 0.f);
    o.y = fmaxf(fmaf(v.y, sc.y, sh.y) + xs.y, 0.f);
    o.z = fmaxf(fmaf(v.z, sc.z, sh.z) + xs.z, 0.f);
    o.w = fmaxf(fmaf(v.w, sc.w, sh.w) + xs.w, 0.f);
    ((float4*)out)[i] = o;
}

// ---------------------------------------------------------------------------
extern "C" void kernel_launch(void* const* d_in, const int* in_sizes, int n_in,
                              void* d_out, int out_size, void* d_ws, size_t ws_size,
                              hipStream_t stream)
{
    const float* x    = (const float*)d_in[0];
    const float* pos  = (const float*)d_in[1];
    const int*   src  = (const int*)d_in[2];           // edge_index row 0
    const float* W_in = (const float*)d_in[3];
    const float* W_out= (const float*)d_in[4];
    const float* pw1  = (const float*)d_in[5];
    const float* pb1  = (const float*)d_in[6];
    const float* pbg  = (const float*)d_in[7];
    const float* pbb  = (const float*)d_in[8];
    const float* pw2  = (const float*)d_in[9];
    const float* pb2  = (const float*)d_in[10];
    const float* a1g  = (const float*)d_in[11];
    const float* a1b  = (const float*)d_in[12];
    const float* aw1  = (const float*)d_in[13];
    const float* ab1  = (const float*)d_in[14];
    const float* a2g  = (const float*)d_in[15];
    const float* a2b  = (const float*)d_in[16];
    const float* aw2  = (const float*)d_in[17];
    const float* ab2  = (const float*)d_in[18];
    const float* linw = (const float*)d_in[19];
    const float* linb = (const float*)d_in[20];
    const float* srcw = (const float*)d_in[21];
    const float* srcb = (const float*)d_in[22];
    const float* dstw = (const float*)d_in[23];
    const float* dstb = (const float*)d_in[24];
    const float* bn1g = (const float*)d_in[25];
    const float* bn1b = (const float*)d_in[26];
    const float* bn2g = (const float*)d_in[27];
    const float* bn2b = (const float*)d_in[28];
    const float* bn3g = (const float*)d_in[29];
    const float* bn3b = (const float*)d_in[30];
    float* outp = (float*)d_out;

    float* ws = (float*)d_ws;
    const size_t NC = (size_t)N_ * C_;
    float* buf_y     = ws;                       // y1, later y3
    float* buf_adst  = ws + NC;                  // a_dst f32; later reused as out
    unsigned short* asrc16 = (unsigned short*)(ws + 2 * NC);       // NC/2 floats
    unsigned short* hw16   = (unsigned short*)(ws + 2 * NC + NC / 2);
    unsigned short* buf_t1 = (unsigned short*)(ws + 3 * NC);       // [E,8] bf16
    float* accb      = ws + 3 * NC + (size_t)E_ * 8;
    // 64 slots each, line-aligned strides:
    float* acc_bn1 = accb;                    // 64 x 128
    float* acc_pos = accb + 64 * 128;         // 64 x 32
    float* acc_a1  = acc_pos + 64 * 32;       // 64 x 128
    float* acc_a2  = acc_a1 + 64 * 128;       // 64 x 32
    float* acc_bn2 = acc_a2 + 64 * 32;        // 64 x 128
    float* acc_bn3 = acc_bn2 + 64 * 128;      // 64 x 128   (total 36864 floats)
    const int ACC_TOTAL = 64 * (128 + 32 + 128 + 32 + 128 + 128);
    // buf_out aliases buf_adst: adst last read by k_edge_t1.
    float* buf_out = buf_adst;

    // 0) zero BN slot accumulators (memset node: graph-capturable, no kernel)
    hipMemsetAsync(accb, 0, (size_t)ACC_TOTAL * sizeof(float), stream);
    // 1) y1 = x @ W_in^T (+ slot bn1 stats)  [MFMA split-bf16]
    k_gemm_tile<<<1024, 256, 0, stream>>>(x, W_in, nullptr, nullptr, nullptr, 0.f,
                                          buf_y, acc_bn1);
    // 2) h = relu(bn1(y1)); asrc16 (bf16) / adst (f32) / hw16 (bf16)  [MFMA]
    k_gemm3_tile<<<1024, 256, 0, stream>>>(buf_y, acc_bn1, bn1g, bn1b,
                                           srcw, srcb, dstw, dstb, linw, linb,
                                           asrc16, buf_adst, hw16);
    // 3) pos-BN stats (slot atomics)
    k_pos_stats<<<1024, 256, 0, stream>>>(pos, src, pw1, pb1, acc_pos);
    // 4) attn_bn1 stats (slot atomics)  [gather-hoisted]
    k_abn1_stats<<<2048, 256, 0, stream>>>(pos, src, asrc16, buf_adst,
                                           pw1, pb1, acc_pos, pbg, pbb,
                                           pw2, pb2, acc_a1);
    // 5) t1 (bf16) + abn2 stats (slot atomics)  [gather-hoisted]
    k_edge_t1<<<2048, 256, 0, stream>>>(pos, src, asrc16, buf_adst,
                                        pw1, pb1, acc_pos, pbg, pbb, pw2, pb2,
                                        acc_a1, a1g, a1b, aw1, ab1,
                                        buf_t1, acc_a2);
    // 6) softmax + weighted aggregate -> out (+ slot bn2 stats)  [gather-hoisted]
    k_node_aggr<<<4096, 256, 0, stream>>>(pos, src, buf_t1, acc_a2, a2g, a2b,
                                          aw2, ab2, hw16, acc_pos, pbg, pbb,
                                          pw1, pb1, pw2, pb2, buf_out, acc_bn2);
    // 7) y3 = relu(bn2(out)) @ W_out^T (+ slot bn3 stats)  [MFMA split-bf16]
    k_gemm_tile<<<1024, 256, 0, stream>>>(buf_out, W_out, acc_bn2, bn2g, bn2b, INV_N,
                                          buf_y, acc_bn3);
    // 8) out = relu(bn3(y3) + x)
    k_final<<<(N_ * C_ / 4) / 256, 256, 0, stream>>>(buf_y, acc_bn3, bn3g, bn3b, x, outp);

    (void)in_sizes; (void)n_in; (void)out_size; (void)ws_size;
}

// Round 6
// 290.931 us; speedup vs baseline: 1.0442x; 1.0442x over previous
//
#include <hip/hip_runtime.h>
#include <cstddef>

constexpr int N_ = 65536;
constexpr int K_ = 16;
constexpr int E_ = N_ * K_;      // 1048576
constexpr int C_ = 64;
#define EPS_ 1e-5f
#define SW 68   // LDS row stride (words) for f32 y-tile
#define INV_N (1.f / 65536.f)
#define INV_E (1.f / 1048576.f)
#define NSLOT 64   // atomic-contention spread (R11 post-mortem: 4 lines -> 534us)

typedef unsigned int uint_t;
typedef float f32x4_t __attribute__((ext_vector_type(4)));
typedef short bf16x8_t __attribute__((ext_vector_type(8)));

// bf16 helpers (RNE pack, cheap unpack)
__device__ __forceinline__ uint_t bf16_rne(float f) {
    uint_t u = __float_as_uint(f);
    return (u + 0x7fffu + ((u >> 16) & 1u)) >> 16;
}
__device__ __forceinline__ float bf16_lo(uint_t p) { return __uint_as_float(p << 16); }
__device__ __forceinline__ float bf16_hi(uint_t p) { return __uint_as_float(p & 0xffff0000u); }
__device__ __forceinline__ uint_t pk2(float a, float b) {
    return bf16_rne(a) | (bf16_rne(b) << 16);
}
// HW packed RNE convert: dst = {bf16(hi)<<16 | bf16(lo)}
__device__ __forceinline__ uint_t cvtpk(float lo, float hi) {
    uint_t r;
    asm("v_cvt_pk_bf16_f32 %0, %1, %2" : "=v"(r) : "v"(lo), "v"(hi));
    return r;
}

// split f32x4 -> hi bf16x4 (packed uint2) + lo residual bf16x4 (packed uint2).
// x ~= hi + lo with |x - hi - lo| <~ 2^-18 |x|  -> split-bf16 GEMM == f32-level.
__device__ __forceinline__ void split4(float4 v, uint2& h, uint2& l) {
    h.x = cvtpk(v.x, v.y); h.y = cvtpk(v.z, v.w);
    float r0 = v.x - bf16_lo(h.x), r1 = v.y - bf16_hi(h.x);
    float r2 = v.z - bf16_lo(h.y), r3 = v.w - bf16_hi(h.y);
    l.x = cvtpk(r0, r1); l.y = cvtpk(r2, r3);
}

// scale/shift from raw summed {sum, sumsq}: s[c]=sum, s[nchp+c]=sumsq
__device__ __forceinline__ void bn_ss(const float* __restrict__ s, int nchp, int c,
                                      float invM, const float* __restrict__ g,
                                      const float* __restrict__ b,
                                      float& sc, float& sh)
{
    float mean = s[c] * invM;
    float var  = fmaxf(s[nchp + c] * invM - mean * mean, 0.f);
    sc = g[c] * rsqrtf(var + EPS_);
    sh = b[c] - mean * sc;
}

// ---------------------------------------------------------------------------
// R15 MFMA GEMM machinery. Tiles stored pre-split as bf16-hi / bf16-lo in
// uint[64][36] LDS. Fragment mapping = edge_t1-verified mfma_f32_16x16x32_bf16:
//   A-frag: lane L holds A[row=L&15][k=(L>>4)*8+j]
//   B-frag: lane L holds W[outcol=L&15][k=(L>>4)*8+j]
//   C     : row=(L>>4)*4+j, col=L&15
#define TS 36   // uint stride of split tiles

__device__ __forceinline__ void stage_x_split(const float* __restrict__ in,
                                              const float* __restrict__ ss,
                                              uint_t* __restrict__ Xh,
                                              uint_t* __restrict__ Xl,
                                              int row0, int t)
{
#pragma unroll
    for (int it = 0; it < 4; ++it) {
        int m = t + 256 * it;
        int r = m >> 4, j = m & 15;
        float4 v = ((const float4*)in)[(size_t)(row0 + r) * 16 + j];
        if (ss) {
            float4 sc = ((const float4*)ss)[j];
            float4 sh = ((const float4*)(ss + 64))[j];
            v.x = fmaxf(fmaf(v.x, sc.x, sh.x), 0.f);
            v.y = fmaxf(fmaf(v.y, sc.y, sh.y), 0.f);
            v.z = fmaxf(fmaf(v.z, sc.z, sh.z), 0.f);
            v.w = fmaxf(fmaf(v.w, sc.w, sh.w), 0.f);
        }
        uint2 h, l; split4(v, h, l);
        *(uint2*)&Xh[r * TS + 2 * j] = h;
        *(uint2*)&Xl[r * TS + 2 * j] = l;
    }
}

__device__ __forceinline__ void stage_w_split(const float* __restrict__ W,
                                              uint_t* __restrict__ Wh,
                                              uint_t* __restrict__ Wl, int t)
{
#pragma unroll
    for (int it = 0; it < 4; ++it) {
        int m = t + 256 * it;
        int r = m >> 4, j = m & 15;
        float4 v = ((const float4*)W)[m];
        uint2 h, l; split4(v, h, l);
        *(uint2*)&Wh[r * TS + 2 * j] = h;
        *(uint2*)&Wl[r * TS + 2 * j] = l;
    }
}

struct AFrag { uint4 h0, h1, l0, l1; };

__device__ __forceinline__ AFrag load_afrag(const uint_t* __restrict__ Xh,
                                            const uint_t* __restrict__ Xl,
                                            int L, int wv)
{
    int cl = L & 15, kb = L >> 4;
    int o = (16 * wv + cl) * TS + kb * 4;
    AFrag a;
    a.h0 = *(const uint4*)&Xh[o]; a.h1 = *(const uint4*)&Xh[o + 16];
    a.l0 = *(const uint4*)&Xl[o]; a.l1 = *(const uint4*)&Xl[o + 16];
    return a;
}

#define MF(A, B, C) __builtin_amdgcn_mfma_f32_16x16x32_bf16( \
        *(const bf16x8_t*)&(A), *(const bf16x8_t*)&(B), (C), 0, 0, 0)

// y = X @ W^T via split-bf16: Xh*Wh + Xl*Wh + Xh*Wl (lo*lo dropped).
__device__ __forceinline__ void mfma_tile(const AFrag& af,
                                          const uint_t* __restrict__ Wh,
                                          const uint_t* __restrict__ Wl,
                                          int L, f32x4_t acc[4])
{
    int cl = L & 15, kb = L >> 4;
#pragma unroll
    for (int ct = 0; ct < 4; ++ct) {
        int o = (ct * 16 + cl) * TS + kb * 4;
        uint4 Bh0 = *(const uint4*)&Wh[o], Bh1 = *(const uint4*)&Wh[o + 16];
        uint4 Bl0 = *(const uint4*)&Wl[o], Bl1 = *(const uint4*)&Wl[o + 16];
        f32x4_t a = {0.f, 0.f, 0.f, 0.f};
        a = MF(af.h0, Bh0, a); a = MF(af.l0, Bh0, a); a = MF(af.h0, Bl0, a);
        a = MF(af.h1, Bh1, a); a = MF(af.l1, Bh1, a); a = MF(af.h1, Bl1, a);
        acc[ct] = a;
    }
}

__device__ __forceinline__ void ytile_store(float* __restrict__ ybuf, int L, int wv,
                                            const f32x4_t acc[4])
{
    int cl = L & 15, kb = L >> 4;
#pragma unroll
    for (int ct = 0; ct < 4; ++ct)
#pragma unroll
        for (int j = 0; j < 4; ++j)
            ybuf[(16 * wv + kb * 4 + j) * SW + ct * 16 + cl] = acc[ct][j];
}

// y = (optional relu(bn_from_slots(in))) @ W^T, MFMA split-bf16.
// Output column stats -> slot-spread atomicAdd.
__global__ __launch_bounds__(256)
void k_gemm_tile(const float* __restrict__ in, const float* __restrict__ W,
                 const float* __restrict__ acc_in, const float* __restrict__ g_in,
                 const float* __restrict__ b_in, float invM_in,
                 float* __restrict__ out, float* __restrict__ acc_out)
{
    __shared__ __align__(16) uint_t shb[4 * 64 * TS];   // 36864 B
    __shared__ float ssm[128];
    __shared__ float raws[128];
    uint_t* Xh = shb;           uint_t* Xl = shb + 64 * TS;
    uint_t* Wh = shb + 2 * 64 * TS; uint_t* Wl = shb + 3 * 64 * TS;
    float* ybuf = (float*)shb;                        // [64][SW] f32, aliases Xh/Xl
    float4* scr = (float4*)((float*)shb + 4352);      // after ybuf; aliases Wh (reads done)
    int t = threadIdx.x, L = t & 63, wv = t >> 6;
    int row0 = blockIdx.x * 64;
    if (acc_in) {
        if (t < 128) {
            float s = 0.f;
            for (int sl = 0; sl < NSLOT; ++sl) s += acc_in[sl * 128 + t];
            raws[t] = s;
        }
        __syncthreads();
        if (t < 64) {
            float scv, shv;
            bn_ss(raws, 64, t, invM_in, g_in, b_in, scv, shv);
            ssm[t] = scv; ssm[64 + t] = shv;
        }
    }
    __syncthreads();
    stage_x_split(in, acc_in ? ssm : nullptr, Xh, Xl, row0, t);
    stage_w_split(W, Wh, Wl, t);
    __syncthreads();
    AFrag af = load_afrag(Xh, Xl, L, wv);
    f32x4_t acc[4];
    mfma_tile(af, Wh, Wl, L, acc);
    __syncthreads();            // all A/B tile reads done before ybuf overwrite
    ytile_store(ybuf, L, wv, acc);
    __syncthreads();
    float s0 = 0, s1 = 0, s2 = 0, s3 = 0, q0 = 0, q1 = 0, q2 = 0, q3 = 0;
#pragma unroll
    for (int it = 0; it < 4; ++it) {
        int m = t + 256 * it;
        int r = m >> 4, j = m & 15;
        float4 v = *(const float4*)&ybuf[r * SW + 4 * j];
        ((float4*)out)[(size_t)(row0 + r) * 16 + j] = v;
        s0 += v.x; q0 = fmaf(v.x, v.x, q0);
        s1 += v.y; q1 = fmaf(v.y, v.y, q1);
        s2 += v.z; q2 = fmaf(v.z, v.z, q2);
        s3 += v.w; q3 = fmaf(v.w, v.w, q3);
    }
    scr[t]       = make_float4(s0, s1, s2, s3);   // disjoint from ybuf reads
    scr[256 + t] = make_float4(q0, q1, q2, q3);
    __syncthreads();
    if (t < 16) {   // thread t handles channels 4t..4t+3
        float4 S = make_float4(0, 0, 0, 0), Q = make_float4(0, 0, 0, 0);
#pragma unroll
        for (int k = 0; k < 16; ++k) {
            float4 a = scr[k * 16 + t], b = scr[256 + k * 16 + t];
            S.x += a.x; S.y += a.y; S.z += a.z; S.w += a.w;
            Q.x += b.x; Q.y += b.y; Q.z += b.z; Q.w += b.w;
        }
        float* ao = acc_out + (blockIdx.x & (NSLOT - 1)) * 128;
        atomicAdd(&ao[4 * t + 0], S.x); atomicAdd(&ao[4 * t + 1], S.y);
        atomicAdd(&ao[4 * t + 2], S.z); atomicAdd(&ao[4 * t + 3], S.w);
        atomicAdd(&ao[64 + 4 * t + 0], Q.x); atomicAdd(&ao[64 + 4 * t + 1], Q.y);
        atomicAdd(&ao[64 + 4 * t + 2], Q.z); atomicAdd(&ao[64 + 4 * t + 3], Q.w);
    }
}

// h = relu(bn1(y)) [bn1 from slots]; asrc16 = bf16(h@Wa^T+ba);
// adst = h@Wb^T+bb (f32); hw16 = bf16(h@Wc^T+bc). All three GEMMs MFMA
// split-bf16; A-frags (h) loaded once into regs and reused.
__global__ __launch_bounds__(256)
void k_gemm3_tile(const float* __restrict__ y, const float* __restrict__ acc1,
                  const float* __restrict__ g1, const float* __restrict__ b1,
                  const float* __restrict__ Wa, const float* __restrict__ ba,
                  const float* __restrict__ Wb, const float* __restrict__ bb,
                  const float* __restrict__ Wc, const float* __restrict__ bc,
                  unsigned short* __restrict__ oa16, float* __restrict__ ob,
                  unsigned short* __restrict__ oc16)
{
    __shared__ __align__(16) uint_t shb[4 * 64 * TS];
    __shared__ float ssm[128];
    __shared__ float raws[128];
    uint_t* Xh = shb;           uint_t* Xl = shb + 64 * TS;
    uint_t* Wh = shb + 2 * 64 * TS; uint_t* Wl = shb + 3 * 64 * TS;
    float* ybuf = (float*)shb;
    int t = threadIdx.x, L = t & 63, wv = t >> 6;
    int row0 = blockIdx.x * 64;
    if (t < 128) {
        float s = 0.f;
        for (int sl = 0; sl < NSLOT; ++sl) s += acc1[sl * 128 + t];
        raws[t] = s;
    }
    __syncthreads();
    if (t < 64) {
        float scv, shv;
        bn_ss(raws, 64, t, INV_N, g1, b1, scv, shv);
        ssm[t] = scv; ssm[64 + t] = shv;
    }
    __syncthreads();
    stage_x_split(y, ssm, Xh, Xl, row0, t);
    stage_w_split(Wa, Wh, Wl, t);
    __syncthreads();
    AFrag af = load_afrag(Xh, Xl, L, wv);   // persists in regs across all 3 GEMMs
    f32x4_t acc[4];
    // ---- GEMM a -> bf16 out
    mfma_tile(af, Wh, Wl, L, acc);
    __syncthreads();
    ytile_store(ybuf, L, wv, acc);
    __syncthreads();
#pragma unroll
    for (int it = 0; it < 4; ++it) {
        int m = t + 256 * it;
        int r = m >> 4, j = m & 15;
        float4 v = *(const float4*)&ybuf[r * SW + 4 * j];
        float4 bv = ((const float4*)ba)[j];
        uint2 o;
        o.x = pk2(v.x + bv.x, v.y + bv.y);
        o.y = pk2(v.z + bv.z, v.w + bv.w);
        ((uint2*)oa16)[(size_t)(row0 + r) * 16 + j] = o;
    }
    __syncthreads();
    // ---- GEMM b -> f32 out
    stage_w_split(Wb, Wh, Wl, t);
    __syncthreads();
    mfma_tile(af, Wh, Wl, L, acc);
    __syncthreads();
    ytile_store(ybuf, L, wv, acc);
    __syncthreads();
#pragma unroll
    for (int it = 0; it < 4; ++it) {
        int m = t + 256 * it;
        int r = m >> 4, j = m & 15;
        float4 v = *(const float4*)&ybuf[r * SW + 4 * j];
        float4 bv = ((const float4*)bb)[j];
        v.x += bv.x; v.y += bv.y; v.z += bv.z; v.w += bv.w;
        ((float4*)ob)[(size_t)(row0 + r) * 16 + j] = v;
    }
    __syncthreads();
    // ---- GEMM c -> bf16 out
    stage_w_split(Wc, Wh, Wl, t);
    __syncthreads();
    mfma_tile(af, Wh, Wl, L, acc);
    __syncthreads();
    ytile_store(ybuf, L, wv, acc);
    __syncthreads();
#pragma unroll
    for (int it = 0; it < 4; ++it) {
        int m = t + 256 * it;
        int r = m >> 4, j = m & 15;
        float4 v = *(const float4*)&ybuf[r * SW + 4 * j];
        float4 bv = ((const float4*)bc)[j];
        uint2 o;
        o.x = pk2(v.x + bv.x, v.y + bv.y);
        o.y = pk2(v.z + bv.z, v.w + bv.w);
        ((uint2*)oc16)[(size_t)(row0 + r) * 16 + j] = o;
    }
}

// ---------------------------------------------------------------------------
// Stats of u = rel @ pos_w1^T + pos_b1 over E edges -> slot atomics (8/slot32).
__global__ __launch_bounds__(256)
void k_pos_stats(const float* __restrict__ pos, const int* __restrict__ src,
                 const float* __restrict__ pw1, const float* __restrict__ pb1,
                 float* __restrict__ acc)
{
    float s0 = 0, s1 = 0, s2 = 0, q0 = 0, q1 = 0, q2 = 0;
    int tid = blockIdx.x * 256 + threadIdx.x;
    for (int e = tid; e < E_; e += 1024 * 256) {
        int si = src[e], di = e >> 4;
        float rx = pos[3 * si + 0] - pos[3 * di + 0];
        float ry = pos[3 * si + 1] - pos[3 * di + 1];
        float rz = pos[3 * si + 2] - pos[3 * di + 2];
        float u0 = fmaf(rx, pw1[0], fmaf(ry, pw1[1], fmaf(rz, pw1[2], pb1[0])));
        float u1 = fmaf(rx, pw1[3], fmaf(ry, pw1[4], fmaf(rz, pw1[5], pb1[1])));
        float u2 = fmaf(rx, pw1[6], fmaf(ry, pw1[7], fmaf(rz, pw1[8], pb1[2])));
        s0 += u0; q0 = fmaf(u0, u0, q0);
        s1 += u1; q1 = fmaf(u1, u1, q1);
        s2 += u2; q2 = fmaf(u2, u2, q2);
    }
#pragma unroll
    for (int m = 1; m < 64; m <<= 1) {
        s0 += __shfl_xor(s0, m, 64); s1 += __shfl_xor(s1, m, 64); s2 += __shfl_xor(s2, m, 64);
        q0 += __shfl_xor(q0, m, 64); q1 += __shfl_xor(q1, m, 64); q2 += __shfl_xor(q2, m, 64);
    }
    __shared__ float red[4][8];
    int wv = threadIdx.x >> 6, ln = threadIdx.x & 63;
    if (ln == 0) {
        red[wv][0] = s0; red[wv][1] = s1; red[wv][2] = s2; red[wv][3] = 0.f;
        red[wv][4] = q0; red[wv][5] = q1; red[wv][6] = q2; red[wv][7] = 0.f;
    }
    __syncthreads();
    if (threadIdx.x < 8)
        atomicAdd(&acc[(blockIdx.x & (NSLOT - 1)) * 32 + threadIdx.x],
                  red[0][threadIdx.x] + red[1][threadIdx.x] + red[2][threadIdx.x] + red[3][threadIdx.x]);
}

// ---------------------------------------------------------------------------
// Stats of a = bf16(a_src)[src]-a_dst[dst]+delta. Grid 2048 x 256.
// R17: interleaved gather restored (R16 hoist -> VGPR 132, occupancy 10%);
// pb-fold kept (per-node q, saves 4 adds/iter).
__global__ __launch_bounds__(256)
void k_abn1_stats(const float* __restrict__ pos, const int* __restrict__ src,
                  const unsigned short* __restrict__ asrc16,
                  const float* __restrict__ adst,
                  const float* __restrict__ pw1, const float* __restrict__ pb1,
                  const float* __restrict__ accpos, const float* __restrict__ pbg,
                  const float* __restrict__ pbb, const float* __restrict__ pw2,
                  const float* __restrict__ pb2, float* __restrict__ acc_a1)
{
    __shared__ float rawP[8];
    int t = threadIdx.x;
    int l = t & 15, g = t >> 4, wv = t >> 6;
    int c0 = 4 * l;
    if (t < 8) {
        float s = 0.f;
        for (int sl = 0; sl < NSLOT; ++sl) s += accpos[sl * 32 + t];
        rawP[t] = s;
    }
    __syncthreads();
    float ps0, ph0, ps1, ph1, ps2, ph2;
    bn_ss(rawP, 4, 0, INV_E, pbg, pbb, ps0, ph0);
    bn_ss(rawP, 4, 1, INV_E, pbg, pbb, ps1, ph1);
    bn_ss(rawP, 4, 2, INV_E, pbg, pbb, ps2, ph2);
    float4 p0 = *(const float4*)(pw2 + 12 * l);
    float4 p1 = *(const float4*)(pw2 + 12 * l + 4);
    float4 p2 = *(const float4*)(pw2 + 12 * l + 8);
    float4 pb = *(const float4*)(pb2 + c0);
    float sa0 = 0, sa1 = 0, sa2 = 0, sa3 = 0;
    float qa0 = 0, qa1 = 0, qa2 = 0, qa3 = 0;
#pragma unroll
    for (int nn = 0; nn < 2; ++nn) {
        int n = blockIdx.x * 32 + nn * 16 + g;
        float4 dv = *(const float4*)(adst + (size_t)n * 64 + c0);
        float q0n = pb.x - dv.x, q1n = pb.y - dv.y;
        float q2n = pb.z - dv.z, q3n = pb.w - dv.w;
        float pnx = pos[3 * n + 0], pny = pos[3 * n + 1], pnz = pos[3 * n + 2];
        int si_l = src[n * 16 + l];
        float rx = pos[3 * si_l + 0] - pnx;
        float ry = pos[3 * si_l + 1] - pny;
        float rz = pos[3 * si_l + 2] - pnz;
        float u0 = fmaf(rx, pw1[0], fmaf(ry, pw1[1], fmaf(rz, pw1[2], pb1[0])));
        float u1 = fmaf(rx, pw1[3], fmaf(ry, pw1[4], fmaf(rz, pw1[5], pb1[1])));
        float u2 = fmaf(rx, pw1[6], fmaf(ry, pw1[7], fmaf(rz, pw1[8], pb1[2])));
        float dl0 = fmaxf(fmaf(u0, ps0, ph0), 0.f);
        float dl1 = fmaxf(fmaf(u1, ps1, ph1), 0.f);
        float dl2 = fmaxf(fmaf(u2, ps2, ph2), 0.f);
        for (int k = 0; k < 16; ++k) {
            int si = __shfl(si_l, k, 16);
            float d0 = __shfl(dl0, k, 16);
            float d1 = __shfl(dl1, k, 16);
            float d2 = __shfl(dl2, k, 16);
            uint2 raw = ((const uint2*)asrc16)[(size_t)si * 16 + l];
            float avx = bf16_lo(raw.x), avy = bf16_hi(raw.x);
            float avz = bf16_lo(raw.y), avw = bf16_hi(raw.y);
            float a0 = avx + fmaf(d0, p0.x, fmaf(d1, p0.y, fmaf(d2, p0.z, q0n)));
            float a1 = avy + fmaf(d0, p0.w, fmaf(d1, p1.x, fmaf(d2, p1.y, q1n)));
            float a2 = avz + fmaf(d0, p1.z, fmaf(d1, p1.w, fmaf(d2, p2.x, q2n)));
            float a3 = avw + fmaf(d0, p2.y, fmaf(d1, p2.z, fmaf(d2, p2.w, q3n)));
            sa0 += a0; qa0 = fmaf(a0, a0, qa0);
            sa1 += a1; qa1 = fmaf(a1, a1, qa1);
            sa2 += a2; qa2 = fmaf(a2, a2, qa2);
            sa3 += a3; qa3 = fmaf(a3, a3, qa3);
        }
    }
#pragma unroll
    for (int m = 16; m <= 32; m <<= 1) {
        sa0 += __shfl_xor(sa0, m, 64); sa1 += __shfl_xor(sa1, m, 64);
        sa2 += __shfl_xor(sa2, m, 64); sa3 += __shfl_xor(sa3, m, 64);
        qa0 += __shfl_xor(qa0, m, 64); qa1 += __shfl_xor(qa1, m, 64);
        qa2 += __shfl_xor(qa2, m, 64); qa3 += __shfl_xor(qa3, m, 64);
    }
    __shared__ float red[4][128];
    if ((t & 63) < 16) {
        red[wv][c0 + 0] = sa0; red[wv][c0 + 1] = sa1;
        red[wv][c0 + 2] = sa2; red[wv][c0 + 3] = sa3;
        red[wv][64 + c0 + 0] = qa0; red[wv][64 + c0 + 1] = qa1;
        red[wv][64 + c0 + 2] = qa2; red[wv][64 + c0 + 3] = qa3;
    }
    __syncthreads();
    if (t < 128)
        atomicAdd(&acc_a1[(blockIdx.x & (NSLOT - 1)) * 128 + t],
                  red[0][t] + red[1][t] + red[2][t] + red[3][t]);
}

// ---------------------------------------------------------------------------
// t1 = relu(abn1(a)) @ attn_w1^T + attn_b1; abn2 stats -> slot atomics.
// R17 = R14/R15 structure (43.0us verified: interleaved gather -> swizzled
// LDS tile -> wave-local MFMA) + t1 stored bf16 (stats on pre-round f32).
__global__ __launch_bounds__(256)
void k_edge_t1(const float* __restrict__ pos, const int* __restrict__ src,
               const unsigned short* __restrict__ asrc16,
               const float* __restrict__ adst,
               const float* __restrict__ pw1, const float* __restrict__ pb1,
               const float* __restrict__ accpos, const float* __restrict__ pbg,
               const float* __restrict__ pbb, const float* __restrict__ pw2,
               const float* __restrict__ pb2, const float* __restrict__ acc_a1,
               const float* __restrict__ a1g, const float* __restrict__ a1b,
               const float* __restrict__ aw1, const float* __restrict__ ab1,
               unsigned short* __restrict__ t1, float* __restrict__ acc_a2)
{
    __shared__ uint2 an_lds[4096];   // 32KB: 16 tiles; head aliases rawA1/rawP, later red
    float* shf = (float*)an_lds;
    char*  anb = (char*)an_lds;
    int t = threadIdx.x;
    int l = t & 15, g = t >> 4, wv = t >> 6;
    int L = t & 63;
    int c0 = 4 * l;
    if (t < 128) {
        float s = 0.f;
        for (int sl = 0; sl < NSLOT; ++sl) s += acc_a1[sl * 128 + t];
        shf[t] = s;          // rawA1[0..127]
    } else if (t < 136) {
        int i = t - 128;
        float s = 0.f;
        for (int sl = 0; sl < NSLOT; ++sl) s += accpos[sl * 32 + i];
        shf[128 + i] = s;    // rawP[0..7]
    }
    __syncthreads();
    float ps0, ph0, ps1, ph1, ps2, ph2;
    bn_ss(shf + 128, 4, 0, INV_E, pbg, pbb, ps0, ph0);
    bn_ss(shf + 128, 4, 1, INV_E, pbg, pbb, ps1, ph1);
    bn_ss(shf + 128, 4, 2, INV_E, pbg, pbb, ps2, ph2);
    float scx, shx, scy, shy, scz, shz, scw, shw;
    bn_ss(shf, 64, c0 + 0, INV_E, a1g, a1b, scx, shx);
    bn_ss(shf, 64, c0 + 1, INV_E, a1g, a1b, scy, shy);
    bn_ss(shf, 64, c0 + 2, INV_E, a1g, a1b, scz, shz);
    bn_ss(shf, 64, c0 + 3, INV_E, a1g, a1b, scw, shw);
    // fold BN scale into pw2 rows + pb2:
    // an_c = max(av_c*sc_c + d.(pw2_c*sc_c) + (pb2_c*sc_c + sh_c - dv_c*sc_c), 0)
    float4 p0 = *(const float4*)(pw2 + 12 * l);
    float4 p1 = *(const float4*)(pw2 + 12 * l + 4);
    float4 p2 = *(const float4*)(pw2 + 12 * l + 8);
    float4 pb = *(const float4*)(pb2 + c0);
    float Pa0 = p0.x * scx, Pa1 = p0.y * scx, Pa2 = p0.z * scx;
    float Pb0 = p0.w * scy, Pb1 = p1.x * scy, Pb2 = p1.y * scy;
    float Pc0 = p1.z * scz, Pc1 = p1.w * scz, Pc2 = p2.x * scz;
    float Pd0 = p2.y * scw, Pd1 = p2.z * scw, Pd2 = p2.w * scw;
    float qb0 = fmaf(pb.x, scx, shx);
    float qb1 = fmaf(pb.y, scy, shy);
    float qb2 = fmaf(pb.z, scz, shz);
    float qb3 = fmaf(pb.w, scw, shw);
    // B fragment: lane holds w1[col = L&15][k = (L>>4)*8 + j], 2 K-halves, cols 8..15 zero.
    int col = L & 15, kb = L >> 4;
    uint4 bf0 = make_uint4(0u, 0u, 0u, 0u);
    uint4 bf1 = make_uint4(0u, 0u, 0u, 0u);
    float biasc = 0.f;
    if (col < 8) {
        const float* wr = aw1 + col * 64 + kb * 8;
        bf0 = make_uint4(pk2(wr[0], wr[1]), pk2(wr[2], wr[3]),
                         pk2(wr[4], wr[5]), pk2(wr[6], wr[7]));
        const float* wr2 = wr + 32;
        bf1 = make_uint4(pk2(wr2[0], wr2[1]), pk2(wr2[2], wr2[3]),
                         pk2(wr2[4], wr2[5]), pk2(wr2[6], wr2[7]));
        biasc = ab1[col];
    }
    // A-frag read offsets (bytes within a 2KB tile), XOR-swizzled by row&7.
    int ar = col;
    int aoff0 = ar * 128 + ((kb * 16) ^ ((ar & 7) << 4));
    int aoff1 = ar * 128 + ((64 + kb * 16) ^ ((ar & 7) << 4));
    __syncthreads();   // rawA1/rawP consumed into registers; tiles may overwrite
    float se = 0.f, sq = 0.f;
#pragma unroll
    for (int nn = 0; nn < 2; ++nn) {
        int n = blockIdx.x * 32 + nn * 16 + g;
        float4 dv = *(const float4*)(adst + (size_t)n * 64 + c0);
        float q0n = fmaf(-dv.x, scx, qb0);
        float q1n = fmaf(-dv.y, scy, qb1);
        float q2n = fmaf(-dv.z, scz, qb2);
        float q3n = fmaf(-dv.w, scw, qb3);
        float pnx = pos[3 * n + 0], pny = pos[3 * n + 1], pnz = pos[3 * n + 2];
        int si_l = src[n * 16 + l];
        float rx = pos[3 * si_l + 0] - pnx;
        float ry = pos[3 * si_l + 1] - pny;
        float rz = pos[3 * si_l + 2] - pnz;
        float u0 = fmaf(rx, pw1[0], fmaf(ry, pw1[1], fmaf(rz, pw1[2], pb1[0])));
        float u1 = fmaf(rx, pw1[3], fmaf(ry, pw1[4], fmaf(rz, pw1[5], pb1[1])));
        float u2 = fmaf(rx, pw1[6], fmaf(ry, pw1[7], fmaf(rz, pw1[8], pb1[2])));
        float dl0 = fmaxf(fmaf(u0, ps0, ph0), 0.f);
        float dl1 = fmaxf(fmaf(u1, ps1, ph1), 0.f);
        float dl2 = fmaxf(fmaf(u2, ps2, ph2), 0.f);
#pragma unroll
        for (int k = 0; k < 16; ++k) {
            int si = __shfl(si_l, k, 16);
            float d0 = __shfl(dl0, k, 16);
            float d1 = __shfl(dl1, k, 16);
            float d2 = __shfl(dl2, k, 16);
            uint2 raw = ((const uint2*)asrc16)[(size_t)si * 16 + l];
            float avx = bf16_lo(raw.x), avy = bf16_hi(raw.x);
            float avz = bf16_lo(raw.y), avw = bf16_hi(raw.y);
            float de0 = fmaf(d0, Pa0, fmaf(d1, Pa1, fmaf(d2, Pa2, q0n)));
            float de1 = fmaf(d0, Pb0, fmaf(d1, Pb1, fmaf(d2, Pb2, q1n)));
            float de2 = fmaf(d0, Pc0, fmaf(d1, Pc1, fmaf(d2, Pc2, q2n)));
            float de3 = fmaf(d0, Pd0, fmaf(d1, Pd1, fmaf(d2, Pd2, q3n)));
            float an0 = fmaxf(fmaf(avx, scx, de0), 0.f);
            float an1 = fmaxf(fmaf(avy, scy, de1), 0.f);
            float an2 = fmaxf(fmaf(avz, scz, de2), 0.f);
            float an3 = fmaxf(fmaf(avw, scw, de3), 0.f);
            // pack 4 ch -> bf16 and store to swizzled A tile (wave-local dep)
            int woff = g * 2048 + k * 128 + ((8 * l) ^ ((k & 7) << 4));
            *(uint2*)(anb + woff) = make_uint2(cvtpk(an0, an1), cvtpk(an2, an3));
        }
        // --- MFMA phase: this wave's 4 node-tiles (no cross-wave LDS deps)
#pragma unroll
        for (int tt = 0; tt < 4; ++tt) {
            int g2 = (wv << 2) + tt;
            int tb = g2 * 2048;
            uint4 a0 = *(const uint4*)(anb + tb + aoff0);
            uint4 a1v = *(const uint4*)(anb + tb + aoff1);
            f32x4_t acc = {0.f, 0.f, 0.f, 0.f};
            acc = __builtin_amdgcn_mfma_f32_16x16x32_bf16(
                      *(const bf16x8_t*)&a0, *(const bf16x8_t*)&bf0, acc, 0, 0, 0);
            acc = __builtin_amdgcn_mfma_f32_16x16x32_bf16(
                      *(const bf16x8_t*)&a1v, *(const bf16x8_t*)&bf1, acc, 0, 0, 0);
            if (col < 8) {
                int n2 = blockIdx.x * 32 + nn * 16 + g2;
                unsigned short* op = t1 + (size_t)(n2 * 16 + kb * 4) * 8 + col;
#pragma unroll
                for (int j = 0; j < 4; ++j) {
                    float v = acc[j] + biasc;
                    op[j * 8] = (unsigned short)bf16_rne(v);
                    se += v; sq = fmaf(v, v, sq);
                }
            }
        }
    }
    se += __shfl_xor(se, 16, 64); sq += __shfl_xor(sq, 16, 64);
    se += __shfl_xor(se, 32, 64); sq += __shfl_xor(sq, 32, 64);
    __syncthreads();   // all MFMA tile reads done; reuse LDS head as red[4][16]
    if (L < 8) { shf[wv * 16 + col] = se; shf[wv * 16 + 8 + col] = sq; }
    __syncthreads();
    if (t < 16)
        atomicAdd(&acc_a2[(blockIdx.x & (NSLOT - 1)) * 32 + t],
                  shf[t] + shf[16 + t] + shf[32 + t] + shf[48 + t]);
}

// ---------------------------------------------------------------------------
// Softmax + weighted aggregate, group-per-node; bn2 stats -> slot atomics.
// Grid 4096 x 256 (16 nodes/blk). R17: interleaved gather restored (R16 hoist
// spilled hraw[16] to scratch: +8MB write traffic); t1 read as bf16 kept.
__global__ __launch_bounds__(256)
void k_node_aggr(const float* __restrict__ pos, const int* __restrict__ src,
                 const unsigned short* __restrict__ t1, const float* __restrict__ acc_a2,
                 const float* __restrict__ a2g, const float* __restrict__ a2b,
                 const float* __restrict__ aw2, const float* __restrict__ ab2,
                 const unsigned short* __restrict__ hw16,
                 const float* __restrict__ accpos, const float* __restrict__ pbg,
                 const float* __restrict__ pbb,
                 const float* __restrict__ pw1, const float* __restrict__ pb1,
                 const float* __restrict__ pw2, const float* __restrict__ pb2,
                 float* __restrict__ out, float* __restrict__ acc_bn2)
{
    __shared__ float alds[16][196];   // [group][k*12 + ch8]; later stats scratch
    __shared__ float ssm2[16];
    __shared__ float rawA2[16];
    __shared__ float rawP[8];
    int t = threadIdx.x, l = t & 15, g = t >> 4;
    int c0 = 4 * l;
    if (t < 16) {
        float s = 0.f;
        for (int sl = 0; sl < NSLOT; ++sl) s += acc_a2[sl * 32 + t];
        rawA2[t] = s;
    } else if (t < 24) {
        int i = t - 16;
        float s = 0.f;
        for (int sl = 0; sl < NSLOT; ++sl) s += accpos[sl * 32 + i];
        rawP[i] = s;
    }
    __syncthreads();
    if (t < 8) {
        float scv, shv;
        bn_ss(rawA2, 8, t, INV_E, a2g, a2b, scv, shv);
        ssm2[t] = scv; ssm2[8 + t] = shv;
    }
    __syncthreads();
    float ps0, ph0, ps1, ph1, ps2, ph2;
    bn_ss(rawP, 4, 0, INV_E, pbg, pbb, ps0, ph0);
    bn_ss(rawP, 4, 1, INV_E, pbg, pbb, ps1, ph1);
    bn_ss(rawP, 4, 2, INV_E, pbg, pbb, ps2, ph2);
    float4 p0 = *(const float4*)(pw2 + 12 * l);
    float4 p1 = *(const float4*)(pw2 + 12 * l + 4);
    float4 p2 = *(const float4*)(pw2 + 12 * l + 8);
    float4 pb = *(const float4*)(pb2 + c0);
    int alof = (l & 1) * 4;
    int n = blockIdx.x * 16 + g;
    int e = n * 16 + l;
    // ---- phase A: per-edge attention logits + softmax over the group
    uint4 t4 = ((const uint4*)t1)[e];
    float tv[8] = {bf16_lo(t4.x), bf16_hi(t4.x), bf16_lo(t4.y), bf16_hi(t4.y),
                   bf16_lo(t4.z), bf16_hi(t4.z), bf16_lo(t4.w), bf16_hi(t4.w)};
    float tn[8];
#pragma unroll
    for (int j = 0; j < 8; ++j)
        tn[j] = fmaxf(fmaf(tv[j], ssm2[j], ssm2[8 + j]), 0.f);
    float al[8];
#pragma unroll
    for (int j = 0; j < 8; ++j) {
        float acc = ab2[j];
#pragma unroll
        for (int i = 0; i < 8; ++i) acc = fmaf(tn[i], aw2[j * 8 + i], acc);
        float m = acc;
#pragma unroll
        for (int msk = 1; msk < 16; msk <<= 1) m = fmaxf(m, __shfl_xor(m, msk, 64));
        float ex = __expf(acc - m);
        float sm = ex;
#pragma unroll
        for (int msk = 1; msk < 16; msk <<= 1) sm += __shfl_xor(sm, msk, 64);
        al[j] = ex / sm;
    }
    *(float4*)&alds[g][l * 12]     = make_float4(al[0], al[1], al[2], al[3]);
    *(float4*)&alds[g][l * 12 + 4] = make_float4(al[4], al[5], al[6], al[7]);
    int silane = src[e];
    float pnx = pos[3 * n + 0], pny = pos[3 * n + 1], pnz = pos[3 * n + 2];
    // own-edge d
    float rx = pos[3 * silane + 0] - pnx;
    float ry = pos[3 * silane + 1] - pny;
    float rz = pos[3 * silane + 2] - pnz;
    float u0 = fmaf(rx, pw1[0], fmaf(ry, pw1[1], fmaf(rz, pw1[2], pb1[0])));
    float u1 = fmaf(rx, pw1[3], fmaf(ry, pw1[4], fmaf(rz, pw1[5], pb1[1])));
    float u2 = fmaf(rx, pw1[6], fmaf(ry, pw1[7], fmaf(rz, pw1[8], pb1[2])));
    float dl0 = fmaxf(fmaf(u0, ps0, ph0), 0.f);
    float dl1 = fmaxf(fmaf(u1, ps1, ph1), 0.f);
    float dl2 = fmaxf(fmaf(u2, ps2, ph2), 0.f);
    // ---- phase B: accumulate own 4 channels over the node's 16 edges
    float a0 = 0.f, a1 = 0.f, a2 = 0.f, a3 = 0.f;
#pragma unroll 4
    for (int k = 0; k < 16; ++k) {
        int sk = __shfl(silane, k, 16);
        float d0 = __shfl(dl0, k, 16);
        float d1 = __shfl(dl1, k, 16);
        float d2 = __shfl(dl2, k, 16);
        uint2 raw = ((const uint2*)hw16)[(size_t)sk * 16 + l];
        float hvx = bf16_lo(raw.x), hvy = bf16_hi(raw.x);
        float hvz = bf16_lo(raw.y), hvw = bf16_hi(raw.y);
        float4 alv = *(const float4*)&alds[g][k * 12 + alof];
        float del0 = fmaf(d0, p0.x, fmaf(d1, p0.y, fmaf(d2, p0.z, pb.x)));
        float del1 = fmaf(d0, p0.w, fmaf(d1, p1.x, fmaf(d2, p1.y, pb.y)));
        float del2 = fmaf(d0, p1.z, fmaf(d1, p1.w, fmaf(d2, p2.x, pb.z)));
        float del3 = fmaf(d0, p2.y, fmaf(d1, p2.z, fmaf(d2, p2.w, pb.w)));
        a0 = fmaf(alv.x, hvx + del0, a0);
        a1 = fmaf(alv.y, hvy + del1, a1);
        a2 = fmaf(alv.z, hvz + del2, a2);
        a3 = fmaf(alv.w, hvw + del3, a3);
    }
    *(float4*)(out + (size_t)n * 64 + c0) = make_float4(a0, a1, a2, a3);
    // ---- bn2 stats: reduce over the block's 16 nodes per channel
    __syncthreads();   // all alds reads done
    float4* scr = (float4*)&alds[0][0];   // 512 float4 <= 3136 floats OK
    scr[g * 16 + l]       = make_float4(a0, a1, a2, a3);
    scr[256 + g * 16 + l] = make_float4(a0 * a0, a1 * a1, a2 * a2, a3 * a3);
    __syncthreads();
    if (t < 16) {   // thread t handles channels 4t..4t+3
        float4 S = make_float4(0, 0, 0, 0), Q = make_float4(0, 0, 0, 0);
#pragma unroll
        for (int k = 0; k < 16; ++k) {
            float4 a = scr[k * 16 + t], b = scr[256 + k * 16 + t];
            S.x += a.x; S.y += a.y; S.z += a.z; S.w += a.w;
            Q.x += b.x; Q.y += b.y; Q.z += b.z; Q.w += b.w;
        }
        float* ao = acc_bn2 + (blockIdx.x & (NSLOT - 1)) * 128;
        atomicAdd(&ao[4 * t + 0], S.x); atomicAdd(&ao[4 * t + 1], S.y);
        atomicAdd(&ao[4 * t + 2], S.z); atomicAdd(&ao[4 * t + 3], S.w);
        atomicAdd(&ao[64 + 4 * t + 0], Q.x); atomicAdd(&ao[64 + 4 * t + 1], Q.y);
        atomicAdd(&ao[64 + 4 * t + 2], Q.z); atomicAdd(&ao[64 + 4 * t + 3], Q.w);
    }
}

// ---------------------------------------------------------------------------
// out = relu(bn3(y3) + x_skip); bn3 from slots.
__global__ __launch_bounds__(256)
void k_final(const float* __restrict__ y3, const float* __restrict__ acc3,
             const float* __restrict__ g3, const float* __restrict__ b3,
             const float* __restrict__ x, float* __restrict__ out)
{
    __shared__ float raws[128];
    __shared__ float ssl[128];
    int t = threadIdx.x;
    if (t < 128) {
        float s = 0.f;
        for (int sl = 0; sl < NSLOT; ++sl) s += acc3[sl * 128 + t];
        raws[t] = s;
    }
    __syncthreads();
    if (t < 64) {
        float scv, shv;
        bn_ss(raws, 64, t, INV_N, g3, b3, scv, shv);
        ssl[t] = scv; ssl[64 + t] = shv;
    }
    __syncthreads();
    int i = blockIdx.x * 256 + t;   // float4 index
    int c4 = i & 15;
    float4 sc = *(const float4*)&ssl[4 * c4];
    float4 sh = *(const float4*)&ssl[64 + 4 * c4];
    float4 v  = ((const float4*)y3)[i];
    float4 xs = ((const float4*)x)[i];
    float4 o;
    o.x = fmaxf(fmaf(v.x, sc.x, sh.x) + xs.x, 0.f);
    o.y = fmaxf(fmaf(v.y, sc.y, sh.y) + xs.y, 0.f);
    o.z = fmaxf(fmaf(v.z, sc.z, sh.z) + xs.z, 0.f);
    o.w = fmaxf(fmaf(v.w, sc.w, sh.w) + xs.w, 0.f);
    ((float4*)out)[i] = o;
}

// ---------------------------------------------------------------------------
extern "C" void kernel_launch(void* const* d_in, const int* in_sizes, int n_in,
                              void* d_out, int out_size, void* d_ws, size_t ws_size,
                              hipStream_t stream)
{
    const float* x    = (const float*)d_in[0];
    const float* pos  = (const float*)d_in[1];
    const int*   src  = (const int*)d_in[2];           // edge_index row 0
    const float* W_in = (const float*)d_in[3];
    const float* W_out= (const float*)d_in[4];
    const float* pw1  = (const float*)d_in[5];
    const float* pb1  = (const float*)d_in[6];
    const float* pbg  = (const float*)d_in[7];
    const float* pbb  = (const float*)d_in[8];
    const float* pw2  = (const float*)d_in[9];
    const float* pb2  = (const float*)d_in[10];
    const float* a1g  = (const float*)d_in[11];
    const float* a1b  = (const float*)d_in[12];
    const float* aw1  = (const float*)d_in[13];
    const float* ab1  = (const float*)d_in[14];
    const float* a2g  = (const float*)d_in[15];
    const float* a2b  = (const float*)d_in[16];
    const float* aw2  = (const float*)d_in[17];
    const float* ab2  = (const float*)d_in[18];
    const float* linw = (const float*)d_in[19];
    const float* linb = (const float*)d_in[20];
    const float* srcw = (const float*)d_in[21];
    const float* srcb = (const float*)d_in[22];
    const float* dstw = (const float*)d_in[23];
    const float* dstb = (const float*)d_in[24];
    const float* bn1g = (const float*)d_in[25];
    const float* bn1b = (const float*)d_in[26];
    const float* bn2g = (const float*)d_in[27];
    const float* bn2b = (const float*)d_in[28];
    const float* bn3g = (const float*)d_in[29];
    const float* bn3b = (const float*)d_in[30];
    float* outp = (float*)d_out;

    float* ws = (float*)d_ws;
    const size_t NC = (size_t)N_ * C_;
    float* buf_y     = ws;                       // y1, later y3
    float* buf_adst  = ws + NC;                  // a_dst f32; later reused as out
    unsigned short* asrc16 = (unsigned short*)(ws + 2 * NC);       // NC/2 floats
    unsigned short* hw16   = (unsigned short*)(ws + 2 * NC + NC / 2);
    unsigned short* buf_t1 = (unsigned short*)(ws + 3 * NC);       // [E,8] bf16
    float* accb      = ws + 3 * NC + (size_t)E_ * 8;
    // 64 slots each, line-aligned strides:
    float* acc_bn1 = accb;                    // 64 x 128
    float* acc_pos = accb + 64 * 128;         // 64 x 32
    float* acc_a1  = acc_pos + 64 * 32;       // 64 x 128
    float* acc_a2  = acc_a1 + 64 * 128;       // 64 x 32
    float* acc_bn2 = acc_a2 + 64 * 32;        // 64 x 128
    float* acc_bn3 = acc_bn2 + 64 * 128;      // 64 x 128   (total 36864 floats)
    const int ACC_TOTAL = 64 * (128 + 32 + 128 + 32 + 128 + 128);
    // buf_out aliases buf_adst: adst last read by k_edge_t1.
    float* buf_out = buf_adst;

    // 0) zero BN slot accumulators (memset node: graph-capturable, no kernel)
    hipMemsetAsync(accb, 0, (size_t)ACC_TOTAL * sizeof(float), stream);
    // 1) y1 = x @ W_in^T (+ slot bn1 stats)  [MFMA split-bf16]
    k_gemm_tile<<<1024, 256, 0, stream>>>(x, W_in, nullptr, nullptr, nullptr, 0.f,
                                          buf_y, acc_bn1);
    // 2) h = relu(bn1(y1)); asrc16 (bf16) / adst (f32) / hw16 (bf16)  [MFMA]
    k_gemm3_tile<<<1024, 256, 0, stream>>>(buf_y, acc_bn1, bn1g, bn1b,
                                           srcw, srcb, dstw, dstb, linw, linb,
                                           asrc16, buf_adst, hw16);
    // 3) pos-BN stats (slot atomics)
    k_pos_stats<<<1024, 256, 0, stream>>>(pos, src, pw1, pb1, acc_pos);
    // 4) attn_bn1 stats (slot atomics)
    k_abn1_stats<<<2048, 256, 0, stream>>>(pos, src, asrc16, buf_adst,
                                           pw1, pb1, acc_pos, pbg, pbb,
                                           pw2, pb2, acc_a1);
    // 5) t1 (bf16) + abn2 stats (slot atomics)
    k_edge_t1<<<2048, 256, 0, stream>>>(pos, src, asrc16, buf_adst,
                                        pw1, pb1, acc_pos, pbg, pbb, pw2, pb2,
                                        acc_a1, a1g, a1b, aw1, ab1,
                                        buf_t1, acc_a2);
    // 6) softmax + weighted aggregate -> out (+ slot bn2 stats)
    k_node_aggr<<<4096, 256, 0, stream>>>(pos, src, buf_t1, acc_a2, a2g, a2b,
                                          aw2, ab2, hw16, acc_pos, pbg, pbb,
                                          pw1, pb1, pw2, pb2, buf_out, acc_bn2);
    // 7) y3 = relu(bn2(out)) @ W_out^T (+ slot bn3 stats)  [MFMA split-bf16]
    k_gemm_tile<<<1024, 256, 0, stream>>>(buf_out, W_out, acc_bn2, bn2g, bn2b, INV_N,
                                          buf_y, acc_bn3);
    // 8) out = relu(bn3(y3) + x)
    k_final<<<(N_ * C_ / 4) / 256, 256, 0, stream>>>(buf_y, acc_bn3, bn3g, bn3b, x, outp);

    (void)in_sizes; (void)n_in; (void)out_size; (void)ws_size;
}

// Round 7
// 274.732 us; speedup vs baseline: 1.1057x; 1.0590x over previous
//
#include <hip/hip_runtime.h>
#include <cstddef>

constexpr int N_ = 65536;
constexpr int K_ = 16;
constexpr int E_ = N_ * K_;      // 1048576
constexpr int C_ = 64;
#define EPS_ 1e-5f
#define SW 68   // LDS row stride (words) for f32 y-tile
#define INV_N (1.f / 65536.f)
#define INV_E (1.f / 1048576.f)
#define NSLOT 64   // atomic-contention spread (R11 post-mortem: 4 lines -> 534us)

typedef unsigned int uint_t;
typedef float f32x4_t __attribute__((ext_vector_type(4)));
typedef short bf16x8_t __attribute__((ext_vector_type(8)));

// bf16 helpers (RNE pack, cheap unpack)
__device__ __forceinline__ uint_t bf16_rne(float f) {
    uint_t u = __float_as_uint(f);
    return (u + 0x7fffu + ((u >> 16) & 1u)) >> 16;
}
__device__ __forceinline__ float bf16_lo(uint_t p) { return __uint_as_float(p << 16); }
__device__ __forceinline__ float bf16_hi(uint_t p) { return __uint_as_float(p & 0xffff0000u); }
__device__ __forceinline__ uint_t pk2(float a, float b) {
    return bf16_rne(a) | (bf16_rne(b) << 16);
}
// HW packed RNE convert: dst = {bf16(hi)<<16 | bf16(lo)}
__device__ __forceinline__ uint_t cvtpk(float lo, float hi) {
    uint_t r;
    asm("v_cvt_pk_bf16_f32 %0, %1, %2" : "=v"(r) : "v"(lo), "v"(hi));
    return r;
}

// split f32x4 -> hi bf16x4 (packed uint2) + lo residual bf16x4 (packed uint2).
// x ~= hi + lo with |x - hi - lo| <~ 2^-18 |x|  -> split-bf16 GEMM == f32-level.
__device__ __forceinline__ void split4(float4 v, uint2& h, uint2& l) {
    h.x = cvtpk(v.x, v.y); h.y = cvtpk(v.z, v.w);
    float r0 = v.x - bf16_lo(h.x), r1 = v.y - bf16_hi(h.x);
    float r2 = v.z - bf16_lo(h.y), r3 = v.w - bf16_hi(h.y);
    l.x = cvtpk(r0, r1); l.y = cvtpk(r2, r3);
}

// scale/shift from raw summed {sum, sumsq}: s[c]=sum, s[nchp+c]=sumsq
__device__ __forceinline__ void bn_ss(const float* __restrict__ s, int nchp, int c,
                                      float invM, const float* __restrict__ g,
                                      const float* __restrict__ b,
                                      float& sc, float& sh)
{
    float mean = s[c] * invM;
    float var  = fmaxf(s[nchp + c] * invM - mean * mean, 0.f);
    sc = g[c] * rsqrtf(var + EPS_);
    sh = b[c] - mean * sc;
}

// ---------------------------------------------------------------------------
// R15 MFMA GEMM machinery. Tiles stored pre-split as bf16-hi / bf16-lo in
// uint[64][36] LDS. Fragment mapping = edge_t1-verified mfma_f32_16x16x32_bf16:
//   A-frag: lane L holds A[row=L&15][k=(L>>4)*8+j]
//   B-frag: lane L holds W[outcol=L&15][k=(L>>4)*8+j]
//   C     : row=(L>>4)*4+j, col=L&15
#define TS 36   // uint stride of split tiles

__device__ __forceinline__ void stage_x_split(const float* __restrict__ in,
                                              const float* __restrict__ ss,
                                              uint_t* __restrict__ Xh,
                                              uint_t* __restrict__ Xl,
                                              int row0, int t)
{
#pragma unroll
    for (int it = 0; it < 4; ++it) {
        int m = t + 256 * it;
        int r = m >> 4, j = m & 15;
        float4 v = ((const float4*)in)[(size_t)(row0 + r) * 16 + j];
        if (ss) {
            float4 sc = ((const float4*)ss)[j];
            float4 sh = ((const float4*)(ss + 64))[j];
            v.x = fmaxf(fmaf(v.x, sc.x, sh.x), 0.f);
            v.y = fmaxf(fmaf(v.y, sc.y, sh.y), 0.f);
            v.z = fmaxf(fmaf(v.z, sc.z, sh.z), 0.f);
            v.w = fmaxf(fmaf(v.w, sc.w, sh.w), 0.f);
        }
        uint2 h, l; split4(v, h, l);
        *(uint2*)&Xh[r * TS + 2 * j] = h;
        *(uint2*)&Xl[r * TS + 2 * j] = l;
    }
}

__device__ __forceinline__ void stage_w_split(const float* __restrict__ W,
                                              uint_t* __restrict__ Wh,
                                              uint_t* __restrict__ Wl, int t)
{
#pragma unroll
    for (int it = 0; it < 4; ++it) {
        int m = t + 256 * it;
        int r = m >> 4, j = m & 15;
        float4 v = ((const float4*)W)[m];
        uint2 h, l; split4(v, h, l);
        *(uint2*)&Wh[r * TS + 2 * j] = h;
        *(uint2*)&Wl[r * TS + 2 * j] = l;
    }
}

struct AFrag { uint4 h0, h1, l0, l1; };

__device__ __forceinline__ AFrag load_afrag(const uint_t* __restrict__ Xh,
                                            const uint_t* __restrict__ Xl,
                                            int L, int wv)
{
    int cl = L & 15, kb = L >> 4;
    int o = (16 * wv + cl) * TS + kb * 4;
    AFrag a;
    a.h0 = *(const uint4*)&Xh[o]; a.h1 = *(const uint4*)&Xh[o + 16];
    a.l0 = *(const uint4*)&Xl[o]; a.l1 = *(const uint4*)&Xl[o + 16];
    return a;
}

#define MF(A, B, C) __builtin_amdgcn_mfma_f32_16x16x32_bf16( \
        *(const bf16x8_t*)&(A), *(const bf16x8_t*)&(B), (C), 0, 0, 0)

// y = X @ W^T via split-bf16: Xh*Wh + Xl*Wh + Xh*Wl (lo*lo dropped).
__device__ __forceinline__ void mfma_tile(const AFrag& af,
                                          const uint_t* __restrict__ Wh,
                                          const uint_t* __restrict__ Wl,
                                          int L, f32x4_t acc[4])
{
    int cl = L & 15, kb = L >> 4;
#pragma unroll
    for (int ct = 0; ct < 4; ++ct) {
        int o = (ct * 16 + cl) * TS + kb * 4;
        uint4 Bh0 = *(const uint4*)&Wh[o], Bh1 = *(const uint4*)&Wh[o + 16];
        uint4 Bl0 = *(const uint4*)&Wl[o], Bl1 = *(const uint4*)&Wl[o + 16];
        f32x4_t a = {0.f, 0.f, 0.f, 0.f};
        a = MF(af.h0, Bh0, a); a = MF(af.l0, Bh0, a); a = MF(af.h0, Bl0, a);
        a = MF(af.h1, Bh1, a); a = MF(af.l1, Bh1, a); a = MF(af.h1, Bl1, a);
        acc[ct] = a;
    }
}

__device__ __forceinline__ void ytile_store(float* __restrict__ ybuf, int L, int wv,
                                            const f32x4_t acc[4])
{
    int cl = L & 15, kb = L >> 4;
#pragma unroll
    for (int ct = 0; ct < 4; ++ct)
#pragma unroll
        for (int j = 0; j < 4; ++j)
            ybuf[(16 * wv + kb * 4 + j) * SW + ct * 16 + cl] = acc[ct][j];
}

// y = (optional relu(bn_from_slots(in))) @ W^T, MFMA split-bf16.
// Output column stats -> slot-spread atomicAdd.
// R18: when pos_ != nullptr, blocks >= 1024 run the (independent) pos-BN
// stats body instead — fused launch hides pos_stats under the GEMM.
__global__ __launch_bounds__(256)
void k_gemm_tile(const float* __restrict__ in, const float* __restrict__ W,
                 const float* __restrict__ acc_in, const float* __restrict__ g_in,
                 const float* __restrict__ b_in, float invM_in,
                 float* __restrict__ out, float* __restrict__ acc_out,
                 const float* __restrict__ pos_, const int* __restrict__ src_,
                 const float* __restrict__ pw1_, const float* __restrict__ pb1_,
                 float* __restrict__ accpos_)
{
    __shared__ __align__(16) uint_t shb[4 * 64 * TS];   // 36864 B
    __shared__ float ssm[128];
    __shared__ float raws[128];
    int t = threadIdx.x;
    if (pos_ != nullptr && blockIdx.x >= 1024) {
        // ---- pos-BN stats body (former k_pos_stats) ----
        float* red = (float*)shb;   // [4][8]
        float s0 = 0, s1 = 0, s2 = 0, q0 = 0, q1 = 0, q2 = 0;
        int tid = (blockIdx.x - 1024) * 256 + t;
        for (int e = tid; e < E_; e += 1024 * 256) {
            int si = src_[e], di = e >> 4;
            float rx = pos_[3 * si + 0] - pos_[3 * di + 0];
            float ry = pos_[3 * si + 1] - pos_[3 * di + 1];
            float rz = pos_[3 * si + 2] - pos_[3 * di + 2];
            float u0 = fmaf(rx, pw1_[0], fmaf(ry, pw1_[1], fmaf(rz, pw1_[2], pb1_[0])));
            float u1 = fmaf(rx, pw1_[3], fmaf(ry, pw1_[4], fmaf(rz, pw1_[5], pb1_[1])));
            float u2 = fmaf(rx, pw1_[6], fmaf(ry, pw1_[7], fmaf(rz, pw1_[8], pb1_[2])));
            s0 += u0; q0 = fmaf(u0, u0, q0);
            s1 += u1; q1 = fmaf(u1, u1, q1);
            s2 += u2; q2 = fmaf(u2, u2, q2);
        }
#pragma unroll
        for (int m = 1; m < 64; m <<= 1) {
            s0 += __shfl_xor(s0, m, 64); s1 += __shfl_xor(s1, m, 64); s2 += __shfl_xor(s2, m, 64);
            q0 += __shfl_xor(q0, m, 64); q1 += __shfl_xor(q1, m, 64); q2 += __shfl_xor(q2, m, 64);
        }
        int wv = t >> 6, ln = t & 63;
        if (ln == 0) {
            red[wv * 8 + 0] = s0; red[wv * 8 + 1] = s1; red[wv * 8 + 2] = s2; red[wv * 8 + 3] = 0.f;
            red[wv * 8 + 4] = q0; red[wv * 8 + 5] = q1; red[wv * 8 + 6] = q2; red[wv * 8 + 7] = 0.f;
        }
        __syncthreads();
        if (t < 8)
            atomicAdd(&accpos_[(blockIdx.x & (NSLOT - 1)) * 32 + t],
                      red[t] + red[8 + t] + red[16 + t] + red[24 + t]);
        return;
    }
    uint_t* Xh = shb;           uint_t* Xl = shb + 64 * TS;
    uint_t* Wh = shb + 2 * 64 * TS; uint_t* Wl = shb + 3 * 64 * TS;
    float* ybuf = (float*)shb;                        // [64][SW] f32, aliases Xh/Xl
    float4* scr = (float4*)((float*)shb + 4352);      // after ybuf; aliases Wh (reads done)
    int L = t & 63, wv = t >> 6;
    int row0 = blockIdx.x * 64;
    if (acc_in) {
        if (t < 128) {
            float s = 0.f;
            for (int sl = 0; sl < NSLOT; ++sl) s += acc_in[sl * 128 + t];
            raws[t] = s;
        }
        __syncthreads();
        if (t < 64) {
            float scv, shv;
            bn_ss(raws, 64, t, invM_in, g_in, b_in, scv, shv);
            ssm[t] = scv; ssm[64 + t] = shv;
        }
    }
    __syncthreads();
    stage_x_split(in, acc_in ? ssm : nullptr, Xh, Xl, row0, t);
    stage_w_split(W, Wh, Wl, t);
    __syncthreads();
    AFrag af = load_afrag(Xh, Xl, L, wv);
    f32x4_t acc[4];
    mfma_tile(af, Wh, Wl, L, acc);
    __syncthreads();            // all A/B tile reads done before ybuf overwrite
    ytile_store(ybuf, L, wv, acc);
    __syncthreads();
    float s0 = 0, s1 = 0, s2 = 0, s3 = 0, q0 = 0, q1 = 0, q2 = 0, q3 = 0;
#pragma unroll
    for (int it = 0; it < 4; ++it) {
        int m = t + 256 * it;
        int r = m >> 4, j = m & 15;
        float4 v = *(const float4*)&ybuf[r * SW + 4 * j];
        ((float4*)out)[(size_t)(row0 + r) * 16 + j] = v;
        s0 += v.x; q0 = fmaf(v.x, v.x, q0);
        s1 += v.y; q1 = fmaf(v.y, v.y, q1);
        s2 += v.z; q2 = fmaf(v.z, v.z, q2);
        s3 += v.w; q3 = fmaf(v.w, v.w, q3);
    }
    scr[t]       = make_float4(s0, s1, s2, s3);   // disjoint from ybuf reads
    scr[256 + t] = make_float4(q0, q1, q2, q3);
    __syncthreads();
    if (t < 16) {   // thread t handles channels 4t..4t+3
        float4 S = make_float4(0, 0, 0, 0), Q = make_float4(0, 0, 0, 0);
#pragma unroll
        for (int k = 0; k < 16; ++k) {
            float4 a = scr[k * 16 + t], b = scr[256 + k * 16 + t];
            S.x += a.x; S.y += a.y; S.z += a.z; S.w += a.w;
            Q.x += b.x; Q.y += b.y; Q.z += b.z; Q.w += b.w;
        }
        float* ao = acc_out + (blockIdx.x & (NSLOT - 1)) * 128;
        atomicAdd(&ao[4 * t + 0], S.x); atomicAdd(&ao[4 * t + 1], S.y);
        atomicAdd(&ao[4 * t + 2], S.z); atomicAdd(&ao[4 * t + 3], S.w);
        atomicAdd(&ao[64 + 4 * t + 0], Q.x); atomicAdd(&ao[64 + 4 * t + 1], Q.y);
        atomicAdd(&ao[64 + 4 * t + 2], Q.z); atomicAdd(&ao[64 + 4 * t + 3], Q.w);
    }
}

// h = relu(bn1(y)) [bn1 from slots]; asrc16 = bf16(h@Wa^T+ba);
// adst16 = bf16(h@Wb^T+bb); hw16 = bf16(h@Wc^T+bc). All three GEMMs MFMA
// split-bf16; A-frags (h) loaded once into regs and reused. R18: adst now
// bf16 (error symmetric to the already-accepted bf16 asrc term of a).
__global__ __launch_bounds__(256)
void k_gemm3_tile(const float* __restrict__ y, const float* __restrict__ acc1,
                  const float* __restrict__ g1, const float* __restrict__ b1,
                  const float* __restrict__ Wa, const float* __restrict__ ba,
                  const float* __restrict__ Wb, const float* __restrict__ bb,
                  const float* __restrict__ Wc, const float* __restrict__ bc,
                  unsigned short* __restrict__ oa16, unsigned short* __restrict__ ob16,
                  unsigned short* __restrict__ oc16)
{
    __shared__ __align__(16) uint_t shb[4 * 64 * TS];
    __shared__ float ssm[128];
    __shared__ float raws[128];
    uint_t* Xh = shb;           uint_t* Xl = shb + 64 * TS;
    uint_t* Wh = shb + 2 * 64 * TS; uint_t* Wl = shb + 3 * 64 * TS;
    float* ybuf = (float*)shb;
    int t = threadIdx.x, L = t & 63, wv = t >> 6;
    int row0 = blockIdx.x * 64;
    if (t < 128) {
        float s = 0.f;
        for (int sl = 0; sl < NSLOT; ++sl) s += acc1[sl * 128 + t];
        raws[t] = s;
    }
    __syncthreads();
    if (t < 64) {
        float scv, shv;
        bn_ss(raws, 64, t, INV_N, g1, b1, scv, shv);
        ssm[t] = scv; ssm[64 + t] = shv;
    }
    __syncthreads();
    stage_x_split(y, ssm, Xh, Xl, row0, t);
    stage_w_split(Wa, Wh, Wl, t);
    __syncthreads();
    AFrag af = load_afrag(Xh, Xl, L, wv);   // persists in regs across all 3 GEMMs
    f32x4_t acc[4];
    // ---- GEMM a -> bf16 out
    mfma_tile(af, Wh, Wl, L, acc);
    __syncthreads();
    ytile_store(ybuf, L, wv, acc);
    __syncthreads();
#pragma unroll
    for (int it = 0; it < 4; ++it) {
        int m = t + 256 * it;
        int r = m >> 4, j = m & 15;
        float4 v = *(const float4*)&ybuf[r * SW + 4 * j];
        float4 bv = ((const float4*)ba)[j];
        uint2 o;
        o.x = pk2(v.x + bv.x, v.y + bv.y);
        o.y = pk2(v.z + bv.z, v.w + bv.w);
        ((uint2*)oa16)[(size_t)(row0 + r) * 16 + j] = o;
    }
    __syncthreads();
    // ---- GEMM b -> bf16 out (adst)
    stage_w_split(Wb, Wh, Wl, t);
    __syncthreads();
    mfma_tile(af, Wh, Wl, L, acc);
    __syncthreads();
    ytile_store(ybuf, L, wv, acc);
    __syncthreads();
#pragma unroll
    for (int it = 0; it < 4; ++it) {
        int m = t + 256 * it;
        int r = m >> 4, j = m & 15;
        float4 v = *(const float4*)&ybuf[r * SW + 4 * j];
        float4 bv = ((const float4*)bb)[j];
        uint2 o;
        o.x = pk2(v.x + bv.x, v.y + bv.y);
        o.y = pk2(v.z + bv.z, v.w + bv.w);
        ((uint2*)ob16)[(size_t)(row0 + r) * 16 + j] = o;
    }
    __syncthreads();
    // ---- GEMM c -> bf16 out
    stage_w_split(Wc, Wh, Wl, t);
    __syncthreads();
    mfma_tile(af, Wh, Wl, L, acc);
    __syncthreads();
    ytile_store(ybuf, L, wv, acc);
    __syncthreads();
#pragma unroll
    for (int it = 0; it < 4; ++it) {
        int m = t + 256 * it;
        int r = m >> 4, j = m & 15;
        float4 v = *(const float4*)&ybuf[r * SW + 4 * j];
        float4 bv = ((const float4*)bc)[j];
        uint2 o;
        o.x = pk2(v.x + bv.x, v.y + bv.y);
        o.y = pk2(v.z + bv.z, v.w + bv.w);
        ((uint2*)oc16)[(size_t)(row0 + r) * 16 + j] = o;
    }
}

// ---------------------------------------------------------------------------
// Stats of a = bf16(a_src)[src]-bf16(a_dst)[dst]+delta. Grid 2048 x 256.
// R17 interleaved gather; R18: adst read as bf16 (8 MB less fetch).
__global__ __launch_bounds__(256)
void k_abn1_stats(const float* __restrict__ pos, const int* __restrict__ src,
                  const unsigned short* __restrict__ asrc16,
                  const unsigned short* __restrict__ adst16,
                  const float* __restrict__ pw1, const float* __restrict__ pb1,
                  const float* __restrict__ accpos, const float* __restrict__ pbg,
                  const float* __restrict__ pbb, const float* __restrict__ pw2,
                  const float* __restrict__ pb2, float* __restrict__ acc_a1)
{
    __shared__ float rawP[8];
    int t = threadIdx.x;
    int l = t & 15, g = t >> 4, wv = t >> 6;
    int c0 = 4 * l;
    if (t < 8) {
        float s = 0.f;
        for (int sl = 0; sl < NSLOT; ++sl) s += accpos[sl * 32 + t];
        rawP[t] = s;
    }
    __syncthreads();
    float ps0, ph0, ps1, ph1, ps2, ph2;
    bn_ss(rawP, 4, 0, INV_E, pbg, pbb, ps0, ph0);
    bn_ss(rawP, 4, 1, INV_E, pbg, pbb, ps1, ph1);
    bn_ss(rawP, 4, 2, INV_E, pbg, pbb, ps2, ph2);
    float4 p0 = *(const float4*)(pw2 + 12 * l);
    float4 p1 = *(const float4*)(pw2 + 12 * l + 4);
    float4 p2 = *(const float4*)(pw2 + 12 * l + 8);
    float4 pb = *(const float4*)(pb2 + c0);
    float sa0 = 0, sa1 = 0, sa2 = 0, sa3 = 0;
    float qa0 = 0, qa1 = 0, qa2 = 0, qa3 = 0;
#pragma unroll
    for (int nn = 0; nn < 2; ++nn) {
        int n = blockIdx.x * 32 + nn * 16 + g;
        uint2 dvp = ((const uint2*)adst16)[(size_t)n * 16 + l];
        float q0n = pb.x - bf16_lo(dvp.x), q1n = pb.y - bf16_hi(dvp.x);
        float q2n = pb.z - bf16_lo(dvp.y), q3n = pb.w - bf16_hi(dvp.y);
        float pnx = pos[3 * n + 0], pny = pos[3 * n + 1], pnz = pos[3 * n + 2];
        int si_l = src[n * 16 + l];
        float rx = pos[3 * si_l + 0] - pnx;
        float ry = pos[3 * si_l + 1] - pny;
        float rz = pos[3 * si_l + 2] - pnz;
        float u0 = fmaf(rx, pw1[0], fmaf(ry, pw1[1], fmaf(rz, pw1[2], pb1[0])));
        float u1 = fmaf(rx, pw1[3], fmaf(ry, pw1[4], fmaf(rz, pw1[5], pb1[1])));
        float u2 = fmaf(rx, pw1[6], fmaf(ry, pw1[7], fmaf(rz, pw1[8], pb1[2])));
        float dl0 = fmaxf(fmaf(u0, ps0, ph0), 0.f);
        float dl1 = fmaxf(fmaf(u1, ps1, ph1), 0.f);
        float dl2 = fmaxf(fmaf(u2, ps2, ph2), 0.f);
        for (int k = 0; k < 16; ++k) {
            int si = __shfl(si_l, k, 16);
            float d0 = __shfl(dl0, k, 16);
            float d1 = __shfl(dl1, k, 16);
            float d2 = __shfl(dl2, k, 16);
            uint2 raw = ((const uint2*)asrc16)[(size_t)si * 16 + l];
            float avx = bf16_lo(raw.x), avy = bf16_hi(raw.x);
            float avz = bf16_lo(raw.y), avw = bf16_hi(raw.y);
            float a0 = avx + fmaf(d0, p0.x, fmaf(d1, p0.y, fmaf(d2, p0.z, q0n)));
            float a1 = avy + fmaf(d0, p0.w, fmaf(d1, p1.x, fmaf(d2, p1.y, q1n)));
            float a2 = avz + fmaf(d0, p1.z, fmaf(d1, p1.w, fmaf(d2, p2.x, q2n)));
            float a3 = avw + fmaf(d0, p2.y, fmaf(d1, p2.z, fmaf(d2, p2.w, q3n)));
            sa0 += a0; qa0 = fmaf(a0, a0, qa0);
            sa1 += a1; qa1 = fmaf(a1, a1, qa1);
            sa2 += a2; qa2 = fmaf(a2, a2, qa2);
            sa3 += a3; qa3 = fmaf(a3, a3, qa3);
        }
    }
#pragma unroll
    for (int m = 16; m <= 32; m <<= 1) {
        sa0 += __shfl_xor(sa0, m, 64); sa1 += __shfl_xor(sa1, m, 64);
        sa2 += __shfl_xor(sa2, m, 64); sa3 += __shfl_xor(sa3, m, 64);
        qa0 += __shfl_xor(qa0, m, 64); qa1 += __shfl_xor(qa1, m, 64);
        qa2 += __shfl_xor(qa2, m, 64); qa3 += __shfl_xor(qa3, m, 64);
    }
    __shared__ float red[4][128];
    if ((t & 63) < 16) {
        red[wv][c0 + 0] = sa0; red[wv][c0 + 1] = sa1;
        red[wv][c0 + 2] = sa2; red[wv][c0 + 3] = sa3;
        red[wv][64 + c0 + 0] = qa0; red[wv][64 + c0 + 1] = qa1;
        red[wv][64 + c0 + 2] = qa2; red[wv][64 + c0 + 3] = qa3;
    }
    __syncthreads();
    if (t < 128)
        atomicAdd(&acc_a1[(blockIdx.x & (NSLOT - 1)) * 128 + t],
                  red[0][t] + red[1][t] + red[2][t] + red[3][t]);
}

// ---------------------------------------------------------------------------
// t1 = relu(abn1(a)) @ attn_w1^T + attn_b1; abn2 stats -> slot atomics.
// R14/R15 structure (verified); t1 bf16; R18: adst read as bf16.
__global__ __launch_bounds__(256)
void k_edge_t1(const float* __restrict__ pos, const int* __restrict__ src,
               const unsigned short* __restrict__ asrc16,
               const unsigned short* __restrict__ adst16,
               const float* __restrict__ pw1, const float* __restrict__ pb1,
               const float* __restrict__ accpos, const float* __restrict__ pbg,
               const float* __restrict__ pbb, const float* __restrict__ pw2,
               const float* __restrict__ pb2, const float* __restrict__ acc_a1,
               const float* __restrict__ a1g, const float* __restrict__ a1b,
               const float* __restrict__ aw1, const float* __restrict__ ab1,
               unsigned short* __restrict__ t1, float* __restrict__ acc_a2)
{
    __shared__ uint2 an_lds[4096];   // 32KB: 16 tiles; head aliases rawA1/rawP, later red
    float* shf = (float*)an_lds;
    char*  anb = (char*)an_lds;
    int t = threadIdx.x;
    int l = t & 15, g = t >> 4, wv = t >> 6;
    int L = t & 63;
    int c0 = 4 * l;
    if (t < 128) {
        float s = 0.f;
        for (int sl = 0; sl < NSLOT; ++sl) s += acc_a1[sl * 128 + t];
        shf[t] = s;          // rawA1[0..127]
    } else if (t < 136) {
        int i = t - 128;
        float s = 0.f;
        for (int sl = 0; sl < NSLOT; ++sl) s += accpos[sl * 32 + i];
        shf[128 + i] = s;    // rawP[0..7]
    }
    __syncthreads();
    float ps0, ph0, ps1, ph1, ps2, ph2;
    bn_ss(shf + 128, 4, 0, INV_E, pbg, pbb, ps0, ph0);
    bn_ss(shf + 128, 4, 1, INV_E, pbg, pbb, ps1, ph1);
    bn_ss(shf + 128, 4, 2, INV_E, pbg, pbb, ps2, ph2);
    float scx, shx, scy, shy, scz, shz, scw, shw;
    bn_ss(shf, 64, c0 + 0, INV_E, a1g, a1b, scx, shx);
    bn_ss(shf, 64, c0 + 1, INV_E, a1g, a1b, scy, shy);
    bn_ss(shf, 64, c0 + 2, INV_E, a1g, a1b, scz, shz);
    bn_ss(shf, 64, c0 + 3, INV_E, a1g, a1b, scw, shw);
    // fold BN scale into pw2 rows + pb2:
    // an_c = max(av_c*sc_c + d.(pw2_c*sc_c) + (pb2_c*sc_c + sh_c - dv_c*sc_c), 0)
    float4 p0 = *(const float4*)(pw2 + 12 * l);
    float4 p1 = *(const float4*)(pw2 + 12 * l + 4);
    float4 p2 = *(const float4*)(pw2 + 12 * l + 8);
    float4 pb = *(const float4*)(pb2 + c0);
    float Pa0 = p0.x * scx, Pa1 = p0.y * scx, Pa2 = p0.z * scx;
    float Pb0 = p0.w * scy, Pb1 = p1.x * scy, Pb2 = p1.y * scy;
    float Pc0 = p1.z * scz, Pc1 = p1.w * scz, Pc2 = p2.x * scz;
    float Pd0 = p2.y * scw, Pd1 = p2.z * scw, Pd2 = p2.w * scw;
    float qb0 = fmaf(pb.x, scx, shx);
    float qb1 = fmaf(pb.y, scy, shy);
    float qb2 = fmaf(pb.z, scz, shz);
    float qb3 = fmaf(pb.w, scw, shw);
    // B fragment: lane holds w1[col = L&15][k = (L>>4)*8 + j], 2 K-halves, cols 8..15 zero.
    int col = L & 15, kb = L >> 4;
    uint4 bf0 = make_uint4(0u, 0u, 0u, 0u);
    uint4 bf1 = make_uint4(0u, 0u, 0u, 0u);
    float biasc = 0.f;
    if (col < 8) {
        const float* wr = aw1 + col * 64 + kb * 8;
        bf0 = make_uint4(pk2(wr[0], wr[1]), pk2(wr[2], wr[3]),
                         pk2(wr[4], wr[5]), pk2(wr[6], wr[7]));
        const float* wr2 = wr + 32;
        bf1 = make_uint4(pk2(wr2[0], wr2[1]), pk2(wr2[2], wr2[3]),
                         pk2(wr2[4], wr2[5]), pk2(wr2[6], wr2[7]));
        biasc = ab1[col];
    }
    // A-frag read offsets (bytes within a 2KB tile), XOR-swizzled by row&7.
    int ar = col;
    int aoff0 = ar * 128 + ((kb * 16) ^ ((ar & 7) << 4));
    int aoff1 = ar * 128 + ((64 + kb * 16) ^ ((ar & 7) << 4));
    __syncthreads();   // rawA1/rawP consumed into registers; tiles may overwrite
    float se = 0.f, sq = 0.f;
#pragma unroll
    for (int nn = 0; nn < 2; ++nn) {
        int n = blockIdx.x * 32 + nn * 16 + g;
        uint2 dvp = ((const uint2*)adst16)[(size_t)n * 16 + l];
        float q0n = fmaf(-bf16_lo(dvp.x), scx, qb0);
        float q1n = fmaf(-bf16_hi(dvp.x), scy, qb1);
        float q2n = fmaf(-bf16_lo(dvp.y), scz, qb2);
        float q3n = fmaf(-bf16_hi(dvp.y), scw, qb3);
        float pnx = pos[3 * n + 0], pny = pos[3 * n + 1], pnz = pos[3 * n + 2];
        int si_l = src[n * 16 + l];
        float rx = pos[3 * si_l + 0] - pnx;
        float ry = pos[3 * si_l + 1] - pny;
        float rz = pos[3 * si_l + 2] - pnz;
        float u0 = fmaf(rx, pw1[0], fmaf(ry, pw1[1], fmaf(rz, pw1[2], pb1[0])));
        float u1 = fmaf(rx, pw1[3], fmaf(ry, pw1[4], fmaf(rz, pw1[5], pb1[1])));
        float u2 = fmaf(rx, pw1[6], fmaf(ry, pw1[7], fmaf(rz, pw1[8], pb1[2])));
        float dl0 = fmaxf(fmaf(u0, ps0, ph0), 0.f);
        float dl1 = fmaxf(fmaf(u1, ps1, ph1), 0.f);
        float dl2 = fmaxf(fmaf(u2, ps2, ph2), 0.f);
#pragma unroll
        for (int k = 0; k < 16; ++k) {
            int si = __shfl(si_l, k, 16);
            float d0 = __shfl(dl0, k, 16);
            float d1 = __shfl(dl1, k, 16);
            float d2 = __shfl(dl2, k, 16);
            uint2 raw = ((const uint2*)asrc16)[(size_t)si * 16 + l];
            float avx = bf16_lo(raw.x), avy = bf16_hi(raw.x);
            float avz = bf16_lo(raw.y), avw = bf16_hi(raw.y);
            float de0 = fmaf(d0, Pa0, fmaf(d1, Pa1, fmaf(d2, Pa2, q0n)));
            float de1 = fmaf(d0, Pb0, fmaf(d1, Pb1, fmaf(d2, Pb2, q1n)));
            float de2 = fmaf(d0, Pc0, fmaf(d1, Pc1, fmaf(d2, Pc2, q2n)));
            float de3 = fmaf(d0, Pd0, fmaf(d1, Pd1, fmaf(d2, Pd2, q3n)));
            float an0 = fmaxf(fmaf(avx, scx, de0), 0.f);
            float an1 = fmaxf(fmaf(avy, scy, de1), 0.f);
            float an2 = fmaxf(fmaf(avz, scz, de2), 0.f);
            float an3 = fmaxf(fmaf(avw, scw, de3), 0.f);
            // pack 4 ch -> bf16 and store to swizzled A tile (wave-local dep)
            int woff = g * 2048 + k * 128 + ((8 * l) ^ ((k & 7) << 4));
            *(uint2*)(anb + woff) = make_uint2(cvtpk(an0, an1), cvtpk(an2, an3));
        }
        // --- MFMA phase: this wave's 4 node-tiles (no cross-wave LDS deps)
#pragma unroll
        for (int tt = 0; tt < 4; ++tt) {
            int g2 = (wv << 2) + tt;
            int tb = g2 * 2048;
            uint4 a0 = *(const uint4*)(anb + tb + aoff0);
            uint4 a1v = *(const uint4*)(anb + tb + aoff1);
            f32x4_t acc = {0.f, 0.f, 0.f, 0.f};
            acc = __builtin_amdgcn_mfma_f32_16x16x32_bf16(
                      *(const bf16x8_t*)&a0, *(const bf16x8_t*)&bf0, acc, 0, 0, 0);
            acc = __builtin_amdgcn_mfma_f32_16x16x32_bf16(
                      *(const bf16x8_t*)&a1v, *(const bf16x8_t*)&bf1, acc, 0, 0, 0);
            if (col < 8) {
                int n2 = blockIdx.x * 32 + nn * 16 + g2;
                unsigned short* op = t1 + (size_t)(n2 * 16 + kb * 4) * 8 + col;
#pragma unroll
                for (int j = 0; j < 4; ++j) {
                    float v = acc[j] + biasc;
                    op[j * 8] = (unsigned short)bf16_rne(v);
                    se += v; sq = fmaf(v, v, sq);
                }
            }
        }
    }
    se += __shfl_xor(se, 16, 64); sq += __shfl_xor(sq, 16, 64);
    se += __shfl_xor(se, 32, 64); sq += __shfl_xor(sq, 32, 64);
    __syncthreads();   // all MFMA tile reads done; reuse LDS head as red[4][16]
    if (L < 8) { shf[wv * 16 + col] = se; shf[wv * 16 + 8 + col] = sq; }
    __syncthreads();
    if (t < 16)
        atomicAdd(&acc_a2[(blockIdx.x & (NSLOT - 1)) * 32 + t],
                  shf[t] + shf[16 + t] + shf[32 + t] + shf[48 + t]);
}

// ---------------------------------------------------------------------------
// Softmax + weighted aggregate, group-per-node; bn2 stats -> slot atomics.
// Grid 4096 x 256 (16 nodes/blk). Interleaved gather (R17); t1 bf16.
__global__ __launch_bounds__(256)
void k_node_aggr(const float* __restrict__ pos, const int* __restrict__ src,
                 const unsigned short* __restrict__ t1, const float* __restrict__ acc_a2,
                 const float* __restrict__ a2g, const float* __restrict__ a2b,
                 const float* __restrict__ aw2, const float* __restrict__ ab2,
                 const unsigned short* __restrict__ hw16,
                 const float* __restrict__ accpos, const float* __restrict__ pbg,
                 const float* __restrict__ pbb,
                 const float* __restrict__ pw1, const float* __restrict__ pb1,
                 const float* __restrict__ pw2, const float* __restrict__ pb2,
                 float* __restrict__ out, float* __restrict__ acc_bn2)
{
    __shared__ float alds[16][196];   // [group][k*12 + ch8]; later stats scratch
    __shared__ float ssm2[16];
    __shared__ float rawA2[16];
    __shared__ float rawP[8];
    int t = threadIdx.x, l = t & 15, g = t >> 4;
    int c0 = 4 * l;
    if (t < 16) {
        float s = 0.f;
        for (int sl = 0; sl < NSLOT; ++sl) s += acc_a2[sl * 32 + t];
        rawA2[t] = s;
    } else if (t < 24) {
        int i = t - 16;
        float s = 0.f;
        for (int sl = 0; sl < NSLOT; ++sl) s += accpos[sl * 32 + i];
        rawP[i] = s;
    }
    __syncthreads();
    if (t < 8) {
        float scv, shv;
        bn_ss(rawA2, 8, t, INV_E, a2g, a2b, scv, shv);
        ssm2[t] = scv; ssm2[8 + t] = shv;
    }
    __syncthreads();
    float ps0, ph0, ps1, ph1, ps2, ph2;
    bn_ss(rawP, 4, 0, INV_E, pbg, pbb, ps0, ph0);
    bn_ss(rawP, 4, 1, INV_E, pbg, pbb, ps1, ph1);
    bn_ss(rawP, 4, 2, INV_E, pbg, pbb, ps2, ph2);
    float4 p0 = *(const float4*)(pw2 + 12 * l);
    float4 p1 = *(const float4*)(pw2 + 12 * l + 4);
    float4 p2 = *(const float4*)(pw2 + 12 * l + 8);
    float4 pb = *(const float4*)(pb2 + c0);
    int alof = (l & 1) * 4;
    int n = blockIdx.x * 16 + g;
    int e = n * 16 + l;
    // ---- phase A: per-edge attention logits + softmax over the group
    uint4 t4 = ((const uint4*)t1)[e];
    float tv[8] = {bf16_lo(t4.x), bf16_hi(t4.x), bf16_lo(t4.y), bf16_hi(t4.y),
                   bf16_lo(t4.z), bf16_hi(t4.z), bf16_lo(t4.w), bf16_hi(t4.w)};
    float tn[8];
#pragma unroll
    for (int j = 0; j < 8; ++j)
        tn[j] = fmaxf(fmaf(tv[j], ssm2[j], ssm2[8 + j]), 0.f);
    float al[8];
#pragma unroll
    for (int j = 0; j < 8; ++j) {
        float acc = ab2[j];
#pragma unroll
        for (int i = 0; i < 8; ++i) acc = fmaf(tn[i], aw2[j * 8 + i], acc);
        float m = acc;
#pragma unroll
        for (int msk = 1; msk < 16; msk <<= 1) m = fmaxf(m, __shfl_xor(m, msk, 64));
        float ex = __expf(acc - m);
        float sm = ex;
#pragma unroll
        for (int msk = 1; msk < 16; msk <<= 1) sm += __shfl_xor(sm, msk, 64);
        al[j] = ex / sm;
    }
    *(float4*)&alds[g][l * 12]     = make_float4(al[0], al[1], al[2], al[3]);
    *(float4*)&alds[g][l * 12 + 4] = make_float4(al[4], al[5], al[6], al[7]);
    int silane = src[e];
    float pnx = pos[3 * n + 0], pny = pos[3 * n + 1], pnz = pos[3 * n + 2];
    // own-edge d
    float rx = pos[3 * silane + 0] - pnx;
    float ry = pos[3 * silane + 1] - pny;
    float rz = pos[3 * silane + 2] - pnz;
    float u0 = fmaf(rx, pw1[0], fmaf(ry, pw1[1], fmaf(rz, pw1[2], pb1[0])));
    float u1 = fmaf(rx, pw1[3], fmaf(ry, pw1[4], fmaf(rz, pw1[5], pb1[1])));
    float u2 = fmaf(rx, pw1[6], fmaf(ry, pw1[7], fmaf(rz, pw1[8], pb1[2])));
    float dl0 = fmaxf(fmaf(u0, ps0, ph0), 0.f);
    float dl1 = fmaxf(fmaf(u1, ps1, ph1), 0.f);
    float dl2 = fmaxf(fmaf(u2, ps2, ph2), 0.f);
    // ---- phase B: accumulate own 4 channels over the node's 16 edges
    float a0 = 0.f, a1 = 0.f, a2 = 0.f, a3 = 0.f;
#pragma unroll 4
    for (int k = 0; k < 16; ++k) {
        int sk = __shfl(silane, k, 16);
        float d0 = __shfl(dl0, k, 16);
        float d1 = __shfl(dl1, k, 16);
        float d2 = __shfl(dl2, k, 16);
        uint2 raw = ((const uint2*)hw16)[(size_t)sk * 16 + l];
        float hvx = bf16_lo(raw.x), hvy = bf16_hi(raw.x);
        float hvz = bf16_lo(raw.y), hvw = bf16_hi(raw.y);
        float4 alv = *(const float4*)&alds[g][k * 12 + alof];
        float del0 = fmaf(d0, p0.x, fmaf(d1, p0.y, fmaf(d2, p0.z, pb.x)));
        float del1 = fmaf(d0, p0.w, fmaf(d1, p1.x, fmaf(d2, p1.y, pb.y)));
        float del2 = fmaf(d0, p1.z, fmaf(d1, p1.w, fmaf(d2, p2.x, pb.z)));
        float del3 = fmaf(d0, p2.y, fmaf(d1, p2.z, fmaf(d2, p2.w, pb.w)));
        a0 = fmaf(alv.x, hvx + del0, a0);
        a1 = fmaf(alv.y, hvy + del1, a1);
        a2 = fmaf(alv.z, hvz + del2, a2);
        a3 = fmaf(alv.w, hvw + del3, a3);
    }
    *(float4*)(out + (size_t)n * 64 + c0) = make_float4(a0, a1, a2, a3);
    // ---- bn2 stats: reduce over the block's 16 nodes per channel
    __syncthreads();   // all alds reads done
    float4* scr = (float4*)&alds[0][0];   // 512 float4 <= 3136 floats OK
    scr[g * 16 + l]       = make_float4(a0, a1, a2, a3);
    scr[256 + g * 16 + l] = make_float4(a0 * a0, a1 * a1, a2 * a2, a3 * a3);
    __syncthreads();
    if (t < 16) {   // thread t handles channels 4t..4t+3
        float4 S = make_float4(0, 0, 0, 0), Q = make_float4(0, 0, 0, 0);
#pragma unroll
        for (int k = 0; k < 16; ++k) {
            float4 a = scr[k * 16 + t], b = scr[256 + k * 16 + t];
            S.x += a.x; S.y += a.y; S.z += a.z; S.w += a.w;
            Q.x += b.x; Q.y += b.y; Q.z += b.z; Q.w += b.w;
        }
        float* ao = acc_bn2 + (blockIdx.x & (NSLOT - 1)) * 128;
        atomicAdd(&ao[4 * t + 0], S.x); atomicAdd(&ao[4 * t + 1], S.y);
        atomicAdd(&ao[4 * t + 2], S.z); atomicAdd(&ao[4 * t + 3], S.w);
        atomicAdd(&ao[64 + 4 * t + 0], Q.x); atomicAdd(&ao[64 + 4 * t + 1], Q.y);
        atomicAdd(&ao[64 + 4 * t + 2], Q.z); atomicAdd(&ao[64 + 4 * t + 3], Q.w);
    }
}

// ---------------------------------------------------------------------------
// out = relu(bn3(y3) + x_skip); bn3 from slots.
__global__ __launch_bounds__(256)
void k_final(const float* __restrict__ y3, const float* __restrict__ acc3,
             const float* __restrict__ g3, const float* __restrict__ b3,
             const float* __restrict__ x, float* __restrict__ out)
{
    __shared__ float raws[128];
    __shared__ float ssl[128];
    int t = threadIdx.x;
    if (t < 128) {
        float s = 0.f;
        for (int sl = 0; sl < NSLOT; ++sl) s += acc3[sl * 128 + t];
        raws[t] = s;
    }
    __syncthreads();
    if (t < 64) {
        float scv, shv;
        bn_ss(raws, 64, t, INV_N, g3, b3, scv, shv);
        ssl[t] = scv; ssl[64 + t] = shv;
    }
    __syncthreads();
    int i = blockIdx.x * 256 + t;   // float4 index
    int c4 = i & 15;
    float4 sc = *(const float4*)&ssl[4 * c4];
    float4 sh = *(const float4*)&ssl[64 + 4 * c4];
    float4 v  = ((const float4*)y3)[i];
    float4 xs = ((const float4*)x)[i];
    float4 o;
    o.x = fmaxf(fmaf(v.x, sc.x, sh.x) + xs.x, 0.f);
    o.y = fmaxf(fmaf(v.y, sc.y, sh.y) + xs.y, 0.f);
    o.z = fmaxf(fmaf(v.z, sc.z, sh.z) + xs.z, 0.f);
    o.w = fmaxf(fmaf(v.w, sc.w, sh.w) + xs.w, 0.f);
    ((float4*)out)[i] = o;
}

// ---------------------------------------------------------------------------
extern "C" void kernel_launch(void* const* d_in, const int* in_sizes, int n_in,
                              void* d_out, int out_size, void* d_ws, size_t ws_size,
                              hipStream_t stream)
{
    const float* x    = (const float*)d_in[0];
    const float* pos  = (const float*)d_in[1];
    const int*   src  = (const int*)d_in[2];           // edge_index row 0
    const float* W_in = (const float*)d_in[3];
    const float* W_out= (const float*)d_in[4];
    const float* pw1  = (const float*)d_in[5];
    const float* pb1  = (const float*)d_in[6];
    const float* pbg  = (const float*)d_in[7];
    const float* pbb  = (const float*)d_in[8];
    const float* pw2  = (const float*)d_in[9];
    const float* pb2  = (const float*)d_in[10];
    const float* a1g  = (const float*)d_in[11];
    const float* a1b  = (const float*)d_in[12];
    const float* aw1  = (const float*)d_in[13];
    const float* ab1  = (const float*)d_in[14];
    const float* a2g  = (const float*)d_in[15];
    const float* a2b  = (const float*)d_in[16];
    const float* aw2  = (const float*)d_in[17];
    const float* ab2  = (const float*)d_in[18];
    const float* linw = (const float*)d_in[19];
    const float* linb = (const float*)d_in[20];
    const float* srcw = (const float*)d_in[21];
    const float* srcb = (const float*)d_in[22];
    const float* dstw = (const float*)d_in[23];
    const float* dstb = (const float*)d_in[24];
    const float* bn1g = (const float*)d_in[25];
    const float* bn1b = (const float*)d_in[26];
    const float* bn2g = (const float*)d_in[27];
    const float* bn2b = (const float*)d_in[28];
    const float* bn3g = (const float*)d_in[29];
    const float* bn3b = (const float*)d_in[30];
    float* outp = (float*)d_out;

    float* ws = (float*)d_ws;
    const size_t NC = (size_t)N_ * C_;
    float* buf_y     = ws;                       // y1, later y3
    // adst16 (bf16, 8 MB) occupies the front of the 16 MB slot at ws+NC;
    // buf_out (f32) reuses the full slot after edge_t1's last adst read.
    unsigned short* adst16 = (unsigned short*)(ws + NC);
    float* buf_out   = ws + NC;
    unsigned short* asrc16 = (unsigned short*)(ws + 2 * NC);       // NC/2 floats
    unsigned short* hw16   = (unsigned short*)(ws + 2 * NC + NC / 2);
    unsigned short* buf_t1 = (unsigned short*)(ws + 3 * NC);       // [E,8] bf16
    float* accb      = ws + 3 * NC + (size_t)E_ * 8;
    // 64 slots each, line-aligned strides:
    float* acc_bn1 = accb;                    // 64 x 128
    float* acc_pos = accb + 64 * 128;         // 64 x 32
    float* acc_a1  = acc_pos + 64 * 32;       // 64 x 128
    float* acc_a2  = acc_a1 + 64 * 128;       // 64 x 32
    float* acc_bn2 = acc_a2 + 64 * 32;        // 64 x 128
    float* acc_bn3 = acc_bn2 + 64 * 128;      // 64 x 128   (total 36864 floats)
    const int ACC_TOTAL = 64 * (128 + 32 + 128 + 32 + 128 + 128);

    // 0) zero BN slot accumulators (memset node: graph-capturable, no kernel)
    hipMemsetAsync(accb, 0, (size_t)ACC_TOTAL * sizeof(float), stream);
    // 1) y1 = x @ W_in^T (+ slot bn1 stats)  [MFMA split-bf16]
    //    + fused pos-BN stats in blocks 1024..2047 (independent work)
    k_gemm_tile<<<2048, 256, 0, stream>>>(x, W_in, nullptr, nullptr, nullptr, 0.f,
                                          buf_y, acc_bn1,
                                          pos, src, pw1, pb1, acc_pos);
    // 2) h = relu(bn1(y1)); asrc16 / adst16 / hw16 (all bf16)  [MFMA]
    k_gemm3_tile<<<1024, 256, 0, stream>>>(buf_y, acc_bn1, bn1g, bn1b,
                                           srcw, srcb, dstw, dstb, linw, linb,
                                           asrc16, adst16, hw16);
    // 3) attn_bn1 stats (slot atomics)
    k_abn1_stats<<<2048, 256, 0, stream>>>(pos, src, asrc16, adst16,
                                           pw1, pb1, acc_pos, pbg, pbb,
                                           pw2, pb2, acc_a1);
    // 4) t1 (bf16) + abn2 stats (slot atomics)
    k_edge_t1<<<2048, 256, 0, stream>>>(pos, src, asrc16, adst16,
                                        pw1, pb1, acc_pos, pbg, pbb, pw2, pb2,
                                        acc_a1, a1g, a1b, aw1, ab1,
                                        buf_t1, acc_a2);
    // 5) softmax + weighted aggregate -> out (+ slot bn2 stats)
    k_node_aggr<<<4096, 256, 0, stream>>>(pos, src, buf_t1, acc_a2, a2g, a2b,
                                          aw2, ab2, hw16, acc_pos, pbg, pbb,
                                          pw1, pb1, pw2, pb2, buf_out, acc_bn2);
    // 6) y3 = relu(bn2(out)) @ W_out^T (+ slot bn3 stats)  [MFMA split-bf16]
    k_gemm_tile<<<1024, 256, 0, stream>>>(buf_out, W_out, acc_bn2, bn2g, bn2b, INV_N,
                                          buf_y, acc_bn3,
                                          nullptr, nullptr, nullptr, nullptr, nullptr);
    // 7) out = relu(bn3(y3) + x)
    k_final<<<(N_ * C_ / 4) / 256, 256, 0, stream>>>(buf_y, acc_bn3, bn3g, bn3b, x, outp);

    (void)in_sizes; (void)n_in; (void)out_size; (void)ws_size;
}